// Round 11
// baseline (1868.984 us; speedup 1.0000x reference)
//
#include <hip/hip_runtime.h>
#include <hip/hip_fp8.h>

#define PTS 8192          // B*N = 4*2048 points
#define HDIM 512
#define BN_EPS 1e-4f
#define HSTRB 528         // LDS row stride in BYTES (fp8 cols)
#define TS 256.0f         // tangent-stream scale (keeps JVP streams out of e4m3 subnormals)
#define PPB 8             // points per block

typedef unsigned short u16;
typedef unsigned char u8;
typedef long long i64;
typedef u16 u16x8 __attribute__((ext_vector_type(8)));
typedef short s16x8 __attribute__((ext_vector_type(8)));
typedef float f32x4 __attribute__((ext_vector_type(4)));
typedef float f32x2 __attribute__((ext_vector_type(2)));

__device__ __forceinline__ float bf2f(u16 u) {
  unsigned x = ((unsigned)u) << 16;
  return __builtin_bit_cast(float, x);
}
__device__ __forceinline__ u16 f2bf(float f) {
  unsigned x = __builtin_bit_cast(unsigned, f);
  x += 0x7fffu + ((x >> 16) & 1u);
  return (u16)(x >> 16);
}
__device__ __forceinline__ u8 f2f8(float x) {
  __hip_fp8_e4m3 v(x);
  return __builtin_bit_cast(u8, v);
}
__device__ __forceinline__ float sigf(float x) {
  return __builtin_amdgcn_rcpf(1.f + __expf(-x));
}
__device__ __forceinline__ float fast_tanh(float x) {
  float e = __expf(2.f * x);
  return 1.f - 2.f * __builtin_amdgcn_rcpf(e + 1.f);
}
__device__ __forceinline__ void gl2lds16(const u16* g, u16* l) {
  __builtin_amdgcn_global_load_lds(
      (const __attribute__((address_space(1))) void*)g,
      (__attribute__((address_space(3))) void*)l, 16, 0, 0);
}

// ---------------------------------------------------------------- prep
struct PrepArgs {
  const float *W1, *W2;
  u8 *W1f8, *W2f8;     // fp8 e4m3 [512][512]
  const float* c;
  u16* cb;
  const float *Wg0, *Wg1, *Wg2, *Wb0, *Wb1, *Wb2;
  const float *bg0, *bg1, *bg2;
  u16* Wpack;          // [6*512][64] bf16
  float* bias_pack;    // [3072]
  const float *x, *m1, *v1, *lg1, *be1;
  float *x_cur, *lp_state;
  const float *Wg3, *bg3, *Wb3;
  float *G3, *B3;
  const float *W0, *b0, *b1, *b2, *W3;
  float *E0, *E1, *E2;   // packed epilogue params
};
__global__ void prep_kernel(PrepArgs a) {
  int i = blockIdx.x * 256 + threadIdx.x;   // 0 .. 524287
  if (i < 512 * 512) { a.W1f8[i] = f2f8(a.W1[i]); a.W2f8[i] = f2f8(a.W2[i]); }
  if (i < PTS * 64) a.cb[i] = f2bf(a.c[i]);
  if (i < 6 * 512 * 64) {
    int sec = i >> 15;
    int within = i & 32767;
    int o = within >> 6, k = within & 63;
    const float* src[6] = {a.Wg0, a.Wg1, a.Wg2, a.Wb0, a.Wb1, a.Wb2};
    a.Wpack[i] = f2bf(src[sec][o * 65 + 1 + k]);
  }
  if (i < 3072) {
    int sec = i >> 9, o = i & 511;
    const float* bgl[3] = {a.bg0, a.bg1, a.bg2};
    a.bias_pack[i] = (sec < 3) ? bgl[sec][o] : 0.f;
  }
  if (i < 512) {
    int o = i;
    a.E0[o * 8 + 0] = a.W0[o * 3];
    a.E0[o * 8 + 1] = a.W0[o * 3 + 1];
    a.E0[o * 8 + 2] = a.W0[o * 3 + 2];
    a.E0[o * 8 + 3] = a.b0[o];
    a.E0[o * 8 + 4] = a.Wg0[o * 65];
    a.E0[o * 8 + 5] = a.Wb0[o * 65];
    a.E0[o * 8 + 6] = 0.f; a.E0[o * 8 + 7] = 0.f;
    a.E1[o * 4 + 0] = a.b1[o];
    a.E1[o * 4 + 1] = a.Wg1[o * 65];
    a.E1[o * 4 + 2] = a.Wb1[o * 65];
    a.E1[o * 4 + 3] = 0.f;
    a.E2[o * 8 + 0] = a.b2[o];
    a.E2[o * 8 + 1] = a.Wg2[o * 65];
    a.E2[o * 8 + 2] = a.Wb2[o * 65];
    a.E2[o * 8 + 3] = a.W3[o];
    a.E2[o * 8 + 4] = a.W3[512 + o];
    a.E2[o * 8 + 5] = a.W3[1024 + o];
    a.E2[o * 8 + 6] = 0.f; a.E2[o * 8 + 7] = 0.f;
  }
  if (i < PTS * 3) {
    int d = i % 3;
    a.x_cur[i] = (a.x[i] - a.m1[d]) * __expf(a.lg1[d]) * rsqrtf(a.v1[d] + BN_EPS) + a.be1[d];
  }
  if (i < PTS) a.lp_state[i] = 0.f;
  {
    int lane = threadIdx.x & 63;
    int p = (blockIdx.x * 256 + threadIdx.x) >> 6;   // 0..8191
    float cv = a.c[(size_t)p * 64 + lane];
    float ag[3], ab[3];
    #pragma unroll
    for (int o = 0; o < 3; ++o) {
      ag[o] = cv * a.Wg3[o * 65 + 1 + lane];
      ab[o] = cv * a.Wb3[o * 65 + 1 + lane];
    }
    #pragma unroll
    for (int off = 32; off > 0; off >>= 1) {
      #pragma unroll
      for (int o = 0; o < 3; ++o) {
        ag[o] += __shfl_xor(ag[o], off);
        ab[o] += __shfl_xor(ab[o], off);
      }
    }
    if (lane == 0) {
      #pragma unroll
      for (int o = 0; o < 3; ++o) {
        a.G3[p * 3 + o] = ag[o] + a.bg3[o];
        a.B3[p * 3 + o] = ab[o];
      }
    }
  }
}

// ---------------------------------------------------------------- gates GEMM (bf16, proven)
// Output INTERLEAVED: GBi[layer][p][2*col] = G(+bg), [2*col+1] = Bc.
struct GatesGemmArgs {
  const u16 *A, *W;
  const float* bias;
  u16* GBi;                // [3][8192][1024]
};
__global__ __launch_bounds__(256) void gates_gemm(GatesGemmArgs a) {
  __shared__ u16 As[128 * 32];
  __shared__ u16 Bs[128 * 32];
  int tid = threadIdx.x;
  int m0 = blockIdx.x * 128, n0 = blockIdx.y * 128;
  int wave = tid >> 6, lane = tid & 63;
  int wm = (wave & 1) * 64, wn = (wave >> 1) * 64;
  int lr = lane & 15, quad = lane >> 4;

  int rowS = tid >> 2, colS = (tid & 3) * 8;
  const u16* gA0 = a.A + (size_t)(m0 + rowS) * 64 + colS;
  const u16* gB0 = a.W + (size_t)(n0 + rowS) * 64 + colS;
  u16* sA0 = &As[tid * 8];
  u16* sA1 = &As[2048 + tid * 8];
  u16* sB0 = &Bs[tid * 8];
  u16* sB1 = &Bs[2048 + tid * 8];

  f32x4 acc[4][4];
  #pragma unroll
  for (int i = 0; i < 4; ++i)
    #pragma unroll
    for (int j = 0; j < 4; ++j)
      #pragma unroll
      for (int r = 0; r < 4; ++r) acc[i][j][r] = 0.f;

  for (int k0 = 0; k0 < 64; k0 += 32) {
    if (k0) __syncthreads();
    gl2lds16(gA0 + k0, sA0);
    gl2lds16(gA0 + (size_t)64 * 64 + k0, sA1);
    gl2lds16(gB0 + k0, sB0);
    gl2lds16(gB0 + (size_t)64 * 64 + k0, sB1);
    __syncthreads();
    s16x8 af[4], bfr[4];
    #pragma unroll
    for (int i = 0; i < 4; ++i)
      af[i] = *(const s16x8*)&As[(wm + i * 16 + lr) * 32 + quad * 8];
    #pragma unroll
    for (int j = 0; j < 4; ++j)
      bfr[j] = *(const s16x8*)&Bs[(wn + j * 16 + lr) * 32 + quad * 8];
    #pragma unroll
    for (int i = 0; i < 4; ++i)
      #pragma unroll
      for (int j = 0; j < 4; ++j)
        acc[i][j] = __builtin_amdgcn_mfma_f32_16x16x32_bf16(af[i], bfr[j], acc[i][j], 0, 0, 0);
  }

  #pragma unroll
  for (int j = 0; j < 4; ++j) {
    int n = n0 + wn + j * 16 + lr;
    int sec = n >> 9, col = n & 511;
    int l = (sec < 3) ? sec : sec - 3;
    int off = col * 2 + ((sec < 3) ? 0 : 1);
    float bv = a.bias[n];
    u16* outp = a.GBi + (size_t)l * PTS * 1024 + off;
    #pragma unroll
    for (int i = 0; i < 4; ++i) {
      int mrow = m0 + wm + i * 16 + quad * 4;
      #pragma unroll
      for (int r = 0; r < 4; ++r)
        outp[(size_t)(mrow + r) * 1024] = f2bf(acc[i][j][r] + bv);
    }
  }
}

// ---------------------------------------------------------------- per-stage kernel (fp8 GEMMs)
// 1024 blocks x 512 threads (8 waves); block owns 8 points (32 m-rows).
// LDS ~18.6 KB, VGPR capped at 64 -> 4 blocks/CU = 8 waves/SIMD (2x TLP vs r10).
// Gate loads in epilogues are direct; cross-wave TLP hides their latency.
struct StageArgs {
  const float* sqrtT;
  float ts_prev, ts_cur;
  int mode_prev;             // -1 none, 0,1,2 stage folds, 3 step-end fold
  float* accum6;             // [PTS][6]
  const float *G3, *B3, *Wg3, *Wb3, *b3;
  float *x_cur, *kx, *kl, *lp_state;
  const u16 *GBi0, *GBi1, *GBi2;   // interleaved gate tables [PTS][1024]
  const float *E0, *E1, *E2;       // packed params
  const u8 *W1f8, *W2f8;           // fp8 weights [512][512]
};

__global__ __launch_bounds__(512, 8) void stage_kernel(StageArgs a) {
  __shared__ __align__(16) u8 Hs[(PPB * 4) * HSTRB];   // 16.9 KB (fp8)
  __shared__ float xe[PPB][3];
  __shared__ float part[8][PPB][6];
  int tid = threadIdx.x;
  int w = tid >> 6, lane = tid & 63, lr = lane & 15, quad = lane >> 4;
  int n0 = w * 64;
  int p0 = blockIdx.x * PPB;
  float s0 = a.sqrtT[0];
  float dt = s0 * s0 * (1.f / 3.f);

  // ---- issue L0 gate loads EARLY (independent of fold); wave w -> point w
  int pl0 = w;
  int base_o = lane * 8;
  const u16* g0row = a.GBi0 + (size_t)(p0 + pl0) * 1024 + 2 * base_o;
  u16x8 gc0 = *(const u16x8*)(g0row);
  u16x8 gc1 = *(const u16x8*)(g0row + 8);

  // ---- fold previous stage (thread per point)
  if (tid < PPB) {
    int p = p0 + tid;
    float xc0 = a.x_cur[p * 3], xc1 = a.x_cur[p * 3 + 1], xc2 = a.x_cur[p * 3 + 2];
    float o0 = xc0, o1 = xc1, o2 = xc2;
    if (a.mode_prev >= 0) {
      float tp = a.ts_prev * dt;
      float dx[3], gate[3];
      #pragma unroll
      for (int r = 0; r < 3; ++r) {
        float fr = a.accum6[(size_t)p * 6 + r];
        gate[r] = sigf(a.G3[p * 3 + r] + tp * a.Wg3[r * 65]);
        float bias = a.B3[p * 3 + r] + tp * a.Wb3[r * 65];
        dx[r] = fmaf(fr + a.b3[r], gate[r], bias);
      }
      float klv = -(a.accum6[(size_t)p * 6 + 3] * gate[0] +
                    a.accum6[(size_t)p * 6 + 4] * gate[1] +
                    a.accum6[(size_t)p * 6 + 5] * gate[2]);
      int m = a.mode_prev;
      if (m == 0) {
        o0 = xc0 + 0.5f * dt * dx[0]; o1 = xc1 + 0.5f * dt * dx[1]; o2 = xc2 + 0.5f * dt * dx[2];
        a.kx[p * 3] = dx[0]; a.kx[p * 3 + 1] = dx[1]; a.kx[p * 3 + 2] = dx[2];
        a.kl[p] = klv;
      } else if (m == 1) {
        o0 = xc0 + 0.5f * dt * dx[0]; o1 = xc1 + 0.5f * dt * dx[1]; o2 = xc2 + 0.5f * dt * dx[2];
        a.kx[p * 3] += 2.f * dx[0]; a.kx[p * 3 + 1] += 2.f * dx[1]; a.kx[p * 3 + 2] += 2.f * dx[2];
        a.kl[p] += 2.f * klv;
      } else if (m == 2) {
        o0 = xc0 + dt * dx[0]; o1 = xc1 + dt * dx[1]; o2 = xc2 + dt * dx[2];
        a.kx[p * 3] += 2.f * dx[0]; a.kx[p * 3 + 1] += 2.f * dx[1]; a.kx[p * 3 + 2] += 2.f * dx[2];
        a.kl[p] += 2.f * klv;
      } else {
        float sc = dt * (1.f / 6.f);
        o0 = xc0 + sc * (a.kx[p * 3] + dx[0]);
        o1 = xc1 + sc * (a.kx[p * 3 + 1] + dx[1]);
        o2 = xc2 + sc * (a.kx[p * 3 + 2] + dx[2]);
        a.x_cur[p * 3] = o0; a.x_cur[p * 3 + 1] = o1; a.x_cur[p * 3 + 2] = o2;
        a.lp_state[p] += sc * (a.kl[p] + klv);
      }
    }
    xe[tid][0] = o0; xe[tid][1] = o1; xe[tid][2] = o2;
  }
  __syncthreads();

  float t = a.ts_cur * dt;

  // ---- layer0: wave per point, lane covers 8 cols -> H1 (fp8) in LDS
  // streams 1..3 scaled by TS to stay in e4m3 normal range
  {
    float x0 = xe[pl0][0], x1 = xe[pl0][1], x2 = xe[pl0][2];
    u16x8 gcv[2] = {gc0, gc1};
    unsigned oh[2], od0[2], od1[2], od2[2];
    #pragma unroll
    for (int cc = 0; cc < 2; ++cc) {
      u16x8 v = gcv[cc];
      unsigned ph = 0, p0v = 0, p1v = 0, p2v = 0;
      #pragma unroll
      for (int k = 0; k < 4; ++k) {
        int o = base_o + cc * 4 + k;
        f32x4 e = *(const f32x4*)(a.E0 + (size_t)o * 8);
        f32x2 e2 = *(const f32x2*)(a.E0 + (size_t)o * 8 + 4);
        float u = fmaf(e[0], x0, fmaf(e[1], x1, e[2] * x2)) + e[3];
        float gate = sigf(bf2f(v[2 * k]) + t * e2[0]);
        float bias = bf2f(v[2 * k + 1]) + t * e2[1];
        float z = fmaf(u, gate, bias);
        float h = fast_tanh(z);
        float wm = (1.f - h * h) * gate * TS;
        ph  |= ((unsigned)f2f8(h)) << (8 * k);
        p0v |= ((unsigned)f2f8(wm * e[0])) << (8 * k);
        p1v |= ((unsigned)f2f8(wm * e[1])) << (8 * k);
        p2v |= ((unsigned)f2f8(wm * e[2])) << (8 * k);
      }
      oh[cc] = ph; od0[cc] = p0v; od1[cc] = p1v; od2[cc] = p2v;
    }
    size_t hb = (size_t)(pl0 * 4) * HSTRB + base_o;
    *(unsigned*)(Hs + hb) = oh[0];       *(unsigned*)(Hs + hb + 4) = oh[1];
    *(unsigned*)(Hs + hb + HSTRB) = od0[0];       *(unsigned*)(Hs + hb + HSTRB + 4) = od0[1];
    *(unsigned*)(Hs + hb + 2 * HSTRB) = od1[0];   *(unsigned*)(Hs + hb + 2 * HSTRB + 4) = od1[1];
    *(unsigned*)(Hs + hb + 3 * HSTRB) = od2[0];   *(unsigned*)(Hs + hb + 3 * HSTRB + 4) = od2[1];
  }
  __syncthreads();

  // ---- layer1 GEMM (32m x 64n tile per wave, fp8)
  f32x4 acc[2][4];
  #pragma unroll
  for (int i = 0; i < 2; ++i)
    #pragma unroll
    for (int j = 0; j < 4; ++j)
      #pragma unroll
      for (int r = 0; r < 4; ++r) acc[i][j][r] = 0.f;
  {
    const u8* wp = a.W1f8 + ((size_t)(n0 + lr) * 512 + quad * 8);
    #pragma unroll 2
    for (int k0 = 0; k0 < 512; k0 += 32) {
      i64 bf[4], af[2];
      #pragma unroll
      for (int j = 0; j < 4; ++j)
        bf[j] = *(const i64*)(wp + (size_t)j * 16 * 512 + k0);
      #pragma unroll
      for (int i = 0; i < 2; ++i)
        af[i] = *(const i64*)(Hs + (size_t)(i * 16 + lr) * HSTRB + k0 + quad * 8);
      #pragma unroll
      for (int i = 0; i < 2; ++i)
        #pragma unroll
        for (int j = 0; j < 4; ++j)
          acc[i][j] = __builtin_amdgcn_mfma_f32_16x16x32_fp8_fp8(af[i], bf[j], acc[i][j], 0, 0, 0);
    }
  }
  __syncthreads();   // all H1 reads done

  // ---- epilogue1 -> H2 (fp8) in same LDS (FULLY unrolled; direct gate loads)
  #pragma unroll
  for (int j = 0; j < 4; ++j) {
    int n = n0 + j * 16 + lr;
    f32x4 e1 = *(const f32x4*)(a.E1 + (size_t)n * 4);
    #pragma unroll
    for (int i = 0; i < 2; ++i) {
      int p = p0 + i * 4 + quad;
      unsigned d = *(const unsigned*)(a.GBi1 + (size_t)p * 1024 + 2 * n);
      float gate = sigf(bf2f((u16)(d & 0xffffu)) + t * e1[1]);
      float bias = bf2f((u16)(d >> 16)) + t * e1[2];
      f32x4 u = acc[i][j];
      float z = fmaf(u[0] + e1[0], gate, bias);
      float h = fast_tanh(z);
      float wmf = (1.f - h * h) * gate;
      int row = i * 16 + quad * 4;
      Hs[(size_t)row * HSTRB + n] = f2f8(h);
      Hs[(size_t)(row + 1) * HSTRB + n] = f2f8(u[1] * wmf);
      Hs[(size_t)(row + 2) * HSTRB + n] = f2f8(u[2] * wmf);
      Hs[(size_t)(row + 3) * HSTRB + n] = f2f8(u[3] * wmf);
    }
  }
  __syncthreads();

  // ---- layer2 GEMM (fp8)
  #pragma unroll
  for (int i = 0; i < 2; ++i)
    #pragma unroll
    for (int j = 0; j < 4; ++j)
      #pragma unroll
      for (int r = 0; r < 4; ++r) acc[i][j][r] = 0.f;
  {
    const u8* wp = a.W2f8 + ((size_t)(n0 + lr) * 512 + quad * 8);
    #pragma unroll 2
    for (int k0 = 0; k0 < 512; k0 += 32) {
      i64 bf[4], af[2];
      #pragma unroll
      for (int j = 0; j < 4; ++j)
        bf[j] = *(const i64*)(wp + (size_t)j * 16 * 512 + k0);
      #pragma unroll
      for (int i = 0; i < 2; ++i)
        af[i] = *(const i64*)(Hs + (size_t)(i * 16 + lr) * HSTRB + k0 + quad * 8);
      #pragma unroll
      for (int i = 0; i < 2; ++i)
        #pragma unroll
        for (int j = 0; j < 4; ++j)
          acc[i][j] = __builtin_amdgcn_mfma_f32_16x16x32_fp8_fp8(af[i], bf[j], acc[i][j], 0, 0, 0);
    }
  }

  // ---- epilogue2: gate/tanh + project onto W3 -> 6 partials per point
  #pragma unroll
  for (int i = 0; i < 2; ++i) {
    float v0 = 0.f, v1 = 0.f, v2 = 0.f, v3 = 0.f, v4 = 0.f, v5 = 0.f;
    int pl = i * 4 + quad;
    int p = p0 + pl;
    #pragma unroll
    for (int j = 0; j < 4; ++j) {
      int n = n0 + j * 16 + lr;
      f32x4 ea = *(const f32x4*)(a.E2 + (size_t)n * 8);
      f32x2 eb = *(const f32x2*)(a.E2 + (size_t)n * 8 + 4);
      unsigned d = *(const unsigned*)(a.GBi2 + (size_t)p * 1024 + 2 * n);
      float gate = sigf(bf2f((u16)(d & 0xffffu)) + t * ea[1]);
      float bias = bf2f((u16)(d >> 16)) + t * ea[2];
      f32x4 u = acc[i][j];
      float z = fmaf(u[0] + ea[0], gate, bias);
      float h = fast_tanh(z);
      float wmf = (1.f - h * h) * gate;
      float w30 = ea[3], w31 = eb[0], w32 = eb[1];
      v0 = fmaf(h, w30, v0);
      v1 = fmaf(h, w31, v1);
      v2 = fmaf(h, w32, v2);
      v3 = fmaf(u[1] * wmf, w30, v3);
      v4 = fmaf(u[2] * wmf, w31, v4);
      v5 = fmaf(u[3] * wmf, w32, v5);
    }
    #pragma unroll
    for (int mask = 1; mask <= 8; mask <<= 1) {
      v0 += __shfl_xor(v0, mask);
      v1 += __shfl_xor(v1, mask);
      v2 += __shfl_xor(v2, mask);
      v3 += __shfl_xor(v3, mask);
      v4 += __shfl_xor(v4, mask);
      v5 += __shfl_xor(v5, mask);
    }
    // tangent streams carry TS scale through both GEMMs -> undo here
    float val = (lr == 0) ? v0 : (lr == 1) ? v1 : (lr == 2) ? v2
              : (lr == 3) ? v3 * (1.f / TS) : (lr == 4) ? v4 * (1.f / TS)
              : v5 * (1.f / TS);
    if (lr < 6) part[w][pl][lr] = val;
  }
  __syncthreads();

  if (tid < PPB * 6) {
    int pt = tid / 6, d = tid - pt * 6;
    float sum = 0.f;
    #pragma unroll
    for (int ww = 0; ww < 8; ++ww) sum += part[ww][pt][d];
    a.accum6[(size_t)(p0 + pt) * 6 + d] = sum;
  }
}

// ---------------------------------------------------------------- finalize
struct FinArgs {
  const float* sqrtT;
  const float* accum6;
  const float *G3, *B3, *Wg3, *Wb3, *b3;
  float *x_cur, *kx, *kl, *lp_state;
  const float *m2, *v2, *lg2, *be2;
  float* out_x;
};
__global__ void finalize_kernel(FinArgs a) {
  int p = blockIdx.x * 256 + threadIdx.x;
  if (p >= PTS) return;
  float s0 = a.sqrtT[0];
  float dt = s0 * s0 * (1.f / 3.f);
  float tp = 3.f * dt;
  float dx[3], gate[3];
  #pragma unroll
  for (int r = 0; r < 3; ++r) {
    float fr = a.accum6[(size_t)p * 6 + r];
    gate[r] = sigf(a.G3[p * 3 + r] + tp * a.Wg3[r * 65]);
    float bias = a.B3[p * 3 + r] + tp * a.Wb3[r * 65];
    dx[r] = fmaf(fr + a.b3[r], gate[r], bias);
  }
  float klv = -(a.accum6[(size_t)p * 6 + 3] * gate[0] +
                a.accum6[(size_t)p * 6 + 4] * gate[1] +
                a.accum6[(size_t)p * 6 + 5] * gate[2]);
  float sc = dt * (1.f / 6.f);
  #pragma unroll
  for (int r = 0; r < 3; ++r) {
    float xf = a.x_cur[p * 3 + r] + sc * (a.kx[p * 3 + r] + dx[r]);
    a.out_x[p * 3 + r] = (xf - a.m2[r]) * __expf(a.lg2[r]) * rsqrtf(a.v2[r] + BN_EPS) + a.be2[r];
  }
  a.lp_state[p] += sc * (a.kl[p] + klv);
}

__global__ void finish_lp(const float* __restrict__ lp_state,
                          const float* __restrict__ v1, const float* __restrict__ lg1,
                          const float* __restrict__ v2, const float* __restrict__ lg2,
                          float* __restrict__ out) {
  int b = blockIdx.x, tid = threadIdx.x;
  float s = 0.f;
  for (int n = tid; n < 2048; n += 256) s += lp_state[b * 2048 + n];
  __shared__ float red[256];
  red[tid] = s;
  __syncthreads();
  for (int w = 128; w > 0; w >>= 1) {
    if (tid < w) red[tid] += red[tid + w];
    __syncthreads();
  }
  if (tid == 0) {
    float ld = 0.f;
    for (int d = 0; d < 3; ++d) {
      ld += lg1[d] - 0.5f * logf(v1[d] + BN_EPS);
      ld += lg2[d] - 0.5f * logf(v2[d] + BN_EPS);
    }
    out[b] = red[0] - 2048.f * ld;
  }
}

// ---------------------------------------------------------------- launch
extern "C" void kernel_launch(void* const* d_in, const int* in_sizes, int n_in,
                              void* d_out, int out_size, void* d_ws, size_t ws_size,
                              hipStream_t stream) {
  const float* x        = (const float*)d_in[0];
  const float* c        = (const float*)d_in[1];
  const float* bn1_mean = (const float*)d_in[2];
  const float* bn1_var  = (const float*)d_in[3];
  const float* bn1_lg   = (const float*)d_in[4];
  const float* bn1_beta = (const float*)d_in[5];
  const float* bn2_mean = (const float*)d_in[6];
  const float* bn2_var  = (const float*)d_in[7];
  const float* bn2_lg   = (const float*)d_in[8];
  const float* bn2_beta = (const float*)d_in[9];
  const float* sqrtT    = (const float*)d_in[10];
  const float* W0  = (const float*)d_in[11];
  const float* b0  = (const float*)d_in[12];
  const float* Wg0 = (const float*)d_in[13];
  const float* bg0 = (const float*)d_in[14];
  const float* Wb0 = (const float*)d_in[15];
  const float* W1  = (const float*)d_in[16];
  const float* b1  = (const float*)d_in[17];
  const float* Wg1 = (const float*)d_in[18];
  const float* bg1 = (const float*)d_in[19];
  const float* Wb1 = (const float*)d_in[20];
  const float* W2  = (const float*)d_in[21];
  const float* b2  = (const float*)d_in[22];
  const float* Wg2 = (const float*)d_in[23];
  const float* bg2 = (const float*)d_in[24];
  const float* Wb2 = (const float*)d_in[25];
  const float* W3  = (const float*)d_in[26];
  const float* b3  = (const float*)d_in[27];
  const float* Wg3 = (const float*)d_in[28];
  const float* bg3 = (const float*)d_in[29];
  const float* Wb3 = (const float*)d_in[30];

  char* base = (char*)d_ws;
  size_t off = 0;
  auto alloc = [&](size_t bytes) -> void* {
    void* pp = base + off;
    off += (bytes + 255) & ~(size_t)255;
    return pp;
  };
  u8* W1f8 = (u8*)alloc((size_t)512 * 512);
  u8* W2f8 = (u8*)alloc((size_t)512 * 512);
  u16* cb  = (u16*)alloc((size_t)PTS * 64 * 2);
  u16* Wpack = (u16*)alloc((size_t)6 * 512 * 64 * 2);
  float* bias_pack = (float*)alloc((size_t)3072 * 4);
  u16* GBi = (u16*)alloc((size_t)3 * PTS * 1024 * 2);
  const size_t SZi = (size_t)PTS * 1024;
  u16* GBi0 = GBi;
  u16* GBi1 = GBi + SZi;
  u16* GBi2 = GBi + 2 * SZi;
  float* G3f = (float*)alloc((size_t)PTS * 3 * 4);
  float* B3f = (float*)alloc((size_t)PTS * 3 * 4);
  float* E0 = (float*)alloc((size_t)512 * 8 * 4);
  float* E1 = (float*)alloc((size_t)512 * 4 * 4);
  float* E2 = (float*)alloc((size_t)512 * 8 * 4);
  float* accum6   = (float*)alloc((size_t)PTS * 6 * 4);
  float* x_cur    = (float*)alloc((size_t)PTS * 3 * 4);
  float* kx       = (float*)alloc((size_t)PTS * 3 * 4);
  float* kl       = (float*)alloc((size_t)PTS * 4);
  float* lp_state = (float*)alloc((size_t)PTS * 4);
  (void)ws_size; (void)in_sizes; (void)n_in; (void)out_size;

  PrepArgs pa{W1, W2, W1f8, W2f8, c, cb, Wg0, Wg1, Wg2, Wb0, Wb1, Wb2,
              bg0, bg1, bg2, Wpack, bias_pack, x, bn1_mean, bn1_var,
              bn1_lg, bn1_beta, x_cur, lp_state, Wg3, bg3, Wb3, G3f, B3f,
              W0, b0, b1, b2, W3, E0, E1, E2};
  prep_kernel<<<2048, 256, 0, stream>>>(pa);

  GatesGemmArgs gg{cb, Wpack, bias_pack, GBi};
  gates_gemm<<<dim3(64, 24), 256, 0, stream>>>(gg);

  auto ts_of = [](int s) -> float {
    static const float frac[4] = {0.f, 0.5f, 0.5f, 1.f};
    return (float)(s >> 2) + frac[s & 3];
  };

  for (int s = 0; s < 12; ++s) {
    StageArgs sa{sqrtT, (s == 0) ? 0.f : ts_of(s - 1), ts_of(s),
                 (s == 0) ? -1 : ((s - 1) & 3), accum6,
                 G3f, B3f, Wg3, Wb3, b3, x_cur, kx, kl, lp_state,
                 GBi0, GBi1, GBi2, E0, E1, E2, W1f8, W2f8};
    stage_kernel<<<PTS / PPB, 512, 0, stream>>>(sa);
  }

  FinArgs fa{sqrtT, accum6, G3f, B3f, Wg3, Wb3, b3, x_cur, kx, kl,
             lp_state, bn2_mean, bn2_var, bn2_lg, bn2_beta, (float*)d_out};
  finalize_kernel<<<32, 256, 0, stream>>>(fa);
  finish_lp<<<4, 256, 0, stream>>>(lp_state, bn1_var, bn1_lg, bn2_var, bn2_lg,
                                   (float*)d_out + PTS * 3);
}

// Round 12
// 793.060 us; speedup vs baseline: 2.3567x; 2.3567x over previous
//
#include <hip/hip_runtime.h>
#include <hip/hip_fp8.h>

#define PTS 8192          // B*N = 4*2048 points
#define HDIM 512
#define BN_EPS 1e-4f
#define HSTRB 528         // LDS row stride in BYTES (fp8 cols)
#define TS 256.0f         // tangent-stream scale (keeps JVP streams out of e4m3 subnormals)

typedef unsigned short u16;
typedef unsigned char u8;
typedef long long i64;
typedef u16 u16x8 __attribute__((ext_vector_type(8)));
typedef short s16x8 __attribute__((ext_vector_type(8)));
typedef float f32x4 __attribute__((ext_vector_type(4)));
typedef float f32x2 __attribute__((ext_vector_type(2)));

__device__ __forceinline__ float bf2f(u16 u) {
  unsigned x = ((unsigned)u) << 16;
  return __builtin_bit_cast(float, x);
}
__device__ __forceinline__ u16 f2bf(float f) {
  unsigned x = __builtin_bit_cast(unsigned, f);
  x += 0x7fffu + ((x >> 16) & 1u);
  return (u16)(x >> 16);
}
__device__ __forceinline__ u8 f2f8(float x) {
  __hip_fp8_e4m3 v(x);
  return __builtin_bit_cast(u8, v);
}
__device__ __forceinline__ float sigf(float x) {
  return __builtin_amdgcn_rcpf(1.f + __expf(-x));
}
__device__ __forceinline__ float fast_tanh(float x) {
  float e = __expf(2.f * x);
  return 1.f - 2.f * __builtin_amdgcn_rcpf(e + 1.f);
}
__device__ __forceinline__ void gl2lds16(const u16* g, u16* l) {
  __builtin_amdgcn_global_load_lds(
      (const __attribute__((address_space(1))) void*)g,
      (__attribute__((address_space(3))) void*)l, 16, 0, 0);
}
__device__ __forceinline__ void gl2lds16b(const u8* g, u8* l) {
  __builtin_amdgcn_global_load_lds(
      (const __attribute__((address_space(1))) void*)g,
      (__attribute__((address_space(3))) void*)l, 16, 0, 0);
}

// ---------------------------------------------------------------- prep
struct PrepArgs {
  const float *W1, *W2;
  u8 *W1s, *W2s;       // fp8 e4m3, CHUNK-MAJOR: [16 chunks][512 n][32 B]
  const float* c;
  u16* cb;
  const float *Wg0, *Wg1, *Wg2, *Wb0, *Wb1, *Wb2;
  const float *bg0, *bg1, *bg2;
  u16* Wpack;          // [6*512][64] bf16
  float* bias_pack;    // [3072]
  const float *x, *m1, *v1, *lg1, *be1;
  float *x_cur, *lp_state;
  const float *Wg3, *bg3, *Wb3;
  float *G3, *B3;
  const float *W0, *b0, *b1, *b2, *W3;
  float *E0, *E1, *E2;   // packed epilogue params
};
__global__ void prep_kernel(PrepArgs a) {
  int i = blockIdx.x * 256 + threadIdx.x;   // 0 .. 524287
  if (i < 512 * 512) {
    int n = i >> 9, k = i & 511;
    size_t d = ((size_t)(k >> 5) * 512 + n) * 32 + (k & 31);
    a.W1s[d] = f2f8(a.W1[i]);
    a.W2s[d] = f2f8(a.W2[i]);
  }
  if (i < PTS * 64) a.cb[i] = f2bf(a.c[i]);
  if (i < 6 * 512 * 64) {
    int sec = i >> 15;
    int within = i & 32767;
    int o = within >> 6, k = within & 63;
    const float* src[6] = {a.Wg0, a.Wg1, a.Wg2, a.Wb0, a.Wb1, a.Wb2};
    a.Wpack[i] = f2bf(src[sec][o * 65 + 1 + k]);
  }
  if (i < 3072) {
    int sec = i >> 9, o = i & 511;
    const float* bgl[3] = {a.bg0, a.bg1, a.bg2};
    a.bias_pack[i] = (sec < 3) ? bgl[sec][o] : 0.f;
  }
  if (i < 512) {
    int o = i;
    a.E0[o * 8 + 0] = a.W0[o * 3];
    a.E0[o * 8 + 1] = a.W0[o * 3 + 1];
    a.E0[o * 8 + 2] = a.W0[o * 3 + 2];
    a.E0[o * 8 + 3] = a.b0[o];
    a.E0[o * 8 + 4] = a.Wg0[o * 65];
    a.E0[o * 8 + 5] = a.Wb0[o * 65];
    a.E0[o * 8 + 6] = 0.f; a.E0[o * 8 + 7] = 0.f;
    a.E1[o * 4 + 0] = a.b1[o];
    a.E1[o * 4 + 1] = a.Wg1[o * 65];
    a.E1[o * 4 + 2] = a.Wb1[o * 65];
    a.E1[o * 4 + 3] = 0.f;
    a.E2[o * 8 + 0] = a.b2[o];
    a.E2[o * 8 + 1] = a.Wg2[o * 65];
    a.E2[o * 8 + 2] = a.Wb2[o * 65];
    a.E2[o * 8 + 3] = a.W3[o];
    a.E2[o * 8 + 4] = a.W3[512 + o];
    a.E2[o * 8 + 5] = a.W3[1024 + o];
    a.E2[o * 8 + 6] = 0.f; a.E2[o * 8 + 7] = 0.f;
  }
  if (i < PTS * 3) {
    int d = i % 3;
    a.x_cur[i] = (a.x[i] - a.m1[d]) * __expf(a.lg1[d]) * rsqrtf(a.v1[d] + BN_EPS) + a.be1[d];
  }
  if (i < PTS) a.lp_state[i] = 0.f;
  {
    int lane = threadIdx.x & 63;
    int p = (blockIdx.x * 256 + threadIdx.x) >> 6;   // 0..8191
    float cv = a.c[(size_t)p * 64 + lane];
    float ag[3], ab[3];
    #pragma unroll
    for (int o = 0; o < 3; ++o) {
      ag[o] = cv * a.Wg3[o * 65 + 1 + lane];
      ab[o] = cv * a.Wb3[o * 65 + 1 + lane];
    }
    #pragma unroll
    for (int off = 32; off > 0; off >>= 1) {
      #pragma unroll
      for (int o = 0; o < 3; ++o) {
        ag[o] += __shfl_xor(ag[o], off);
        ab[o] += __shfl_xor(ab[o], off);
      }
    }
    if (lane == 0) {
      #pragma unroll
      for (int o = 0; o < 3; ++o) {
        a.G3[p * 3 + o] = ag[o] + a.bg3[o];
        a.B3[p * 3 + o] = ab[o];
      }
    }
  }
}

// ---------------------------------------------------------------- gates GEMM (bf16, proven)
struct GatesGemmArgs {
  const u16 *A, *W;
  const float* bias;
  u16* GBi;                // [3][8192][1024] interleaved
};
__global__ __launch_bounds__(256) void gates_gemm(GatesGemmArgs a) {
  __shared__ u16 As[128 * 32];
  __shared__ u16 Bs[128 * 32];
  int tid = threadIdx.x;
  int m0 = blockIdx.x * 128, n0 = blockIdx.y * 128;
  int wave = tid >> 6, lane = tid & 63;
  int wm = (wave & 1) * 64, wn = (wave >> 1) * 64;
  int lr = lane & 15, quad = lane >> 4;

  int rowS = tid >> 2, colS = (tid & 3) * 8;
  const u16* gA0 = a.A + (size_t)(m0 + rowS) * 64 + colS;
  const u16* gB0 = a.W + (size_t)(n0 + rowS) * 64 + colS;
  u16* sA0 = &As[tid * 8];
  u16* sA1 = &As[2048 + tid * 8];
  u16* sB0 = &Bs[tid * 8];
  u16* sB1 = &Bs[2048 + tid * 8];

  f32x4 acc[4][4];
  #pragma unroll
  for (int i = 0; i < 4; ++i)
    #pragma unroll
    for (int j = 0; j < 4; ++j)
      #pragma unroll
      for (int r = 0; r < 4; ++r) acc[i][j][r] = 0.f;

  for (int k0 = 0; k0 < 64; k0 += 32) {
    if (k0) __syncthreads();
    gl2lds16(gA0 + k0, sA0);
    gl2lds16(gA0 + (size_t)64 * 64 + k0, sA1);
    gl2lds16(gB0 + k0, sB0);
    gl2lds16(gB0 + (size_t)64 * 64 + k0, sB1);
    __syncthreads();
    s16x8 af[4], bfr[4];
    #pragma unroll
    for (int i = 0; i < 4; ++i)
      af[i] = *(const s16x8*)&As[(wm + i * 16 + lr) * 32 + quad * 8];
    #pragma unroll
    for (int j = 0; j < 4; ++j)
      bfr[j] = *(const s16x8*)&Bs[(wn + j * 16 + lr) * 32 + quad * 8];
    #pragma unroll
    for (int i = 0; i < 4; ++i)
      #pragma unroll
      for (int j = 0; j < 4; ++j)
        acc[i][j] = __builtin_amdgcn_mfma_f32_16x16x32_bf16(af[i], bfr[j], acc[i][j], 0, 0, 0);
  }

  #pragma unroll
  for (int j = 0; j < 4; ++j) {
    int n = n0 + wn + j * 16 + lr;
    int sec = n >> 9, col = n & 511;
    int l = (sec < 3) ? sec : sec - 3;
    int off = col * 2 + ((sec < 3) ? 0 : 1);
    float bv = a.bias[n];
    u16* outp = a.GBi + (size_t)l * PTS * 1024 + off;
    #pragma unroll
    for (int i = 0; i < 4; ++i) {
      int mrow = m0 + wm + i * 16 + quad * 4;
      #pragma unroll
      for (int r = 0; r < 4; ++r)
        outp[(size_t)(mrow + r) * 1024] = f2bf(acc[i][j][r] + bv);
    }
  }
}

// ---------------------------------------------------------------- per-stage kernel (fp8, W via LDS)
// 512 blocks x 512 threads (8 waves); block owns 16 points (64 m-rows).
// W streamed global->LDS (chunk-major, double-buffered gl2lds) - K-loop reads are
// LDS-latency not L2-latency. One barrier per 32-k chunk (m97 pattern).
struct StageArgs {
  const float* sqrtT;
  float ts_prev, ts_cur;
  int mode_prev;             // -1 none, 0,1,2 stage folds, 3 step-end fold
  float* accum6;             // [PTS][6]
  const float *G3, *B3, *Wg3, *Wb3, *b3;
  float *x_cur, *kx, *kl, *lp_state;
  const u16 *GBi0, *GBi1, *GBi2;   // interleaved gate tables [PTS][1024]
  const float *E0, *E1, *E2;       // packed params
  const u8 *W1s, *W2s;             // fp8 weights chunk-major [16][512][32]
};

__global__ __launch_bounds__(512, 4) void stage_kernel(StageArgs a) {
  __shared__ __align__(16) u8 Hs[64 * HSTRB];     // 33.8 KB (fp8 activations)
  __shared__ __align__(16) u8 WsL[2 * 16384];     // 32 KB W chunk double-buffer
  __shared__ float xe[16][3];
  __shared__ float part[8][16][6];
  int tid = threadIdx.x;
  int w = tid >> 6, lane = tid & 63, lr = lane & 15, quad = lane >> 4;
  int n0 = w * 64;
  int p0 = blockIdx.x * 16;
  float s0 = a.sqrtT[0];
  float dt = s0 * s0 * (1.f / 3.f);

  // ---- stage W1 chunk 0 into buf0 immediately (drained by pre-GEMM1 barrier)
  gl2lds16b(a.W1s + tid * 16, WsL + tid * 16);
  gl2lds16b(a.W1s + 8192 + tid * 16, WsL + 8192 + tid * 16);

  // ---- issue L0 gate loads EARLY (independent of fold)
  int pl0 = tid >> 5;
  int base_o = (tid & 31) * 16;
  const u16* g0row = a.GBi0 + (size_t)(p0 + pl0) * 1024 + 2 * base_o;
  u16x8 gc0 = *(const u16x8*)(g0row);
  u16x8 gc1 = *(const u16x8*)(g0row + 8);
  u16x8 gc2 = *(const u16x8*)(g0row + 16);
  u16x8 gc3 = *(const u16x8*)(g0row + 24);

  // ---- fold previous stage (thread per point)
  if (tid < 16) {
    int p = p0 + tid;
    float xc0 = a.x_cur[p * 3], xc1 = a.x_cur[p * 3 + 1], xc2 = a.x_cur[p * 3 + 2];
    float o0 = xc0, o1 = xc1, o2 = xc2;
    if (a.mode_prev >= 0) {
      float tp = a.ts_prev * dt;
      float dx[3], gate[3];
      #pragma unroll
      for (int r = 0; r < 3; ++r) {
        float fr = a.accum6[(size_t)p * 6 + r];
        gate[r] = sigf(a.G3[p * 3 + r] + tp * a.Wg3[r * 65]);
        float bias = a.B3[p * 3 + r] + tp * a.Wb3[r * 65];
        dx[r] = fmaf(fr + a.b3[r], gate[r], bias);
      }
      float klv = -(a.accum6[(size_t)p * 6 + 3] * gate[0] +
                    a.accum6[(size_t)p * 6 + 4] * gate[1] +
                    a.accum6[(size_t)p * 6 + 5] * gate[2]);
      int m = a.mode_prev;
      if (m == 0) {
        o0 = xc0 + 0.5f * dt * dx[0]; o1 = xc1 + 0.5f * dt * dx[1]; o2 = xc2 + 0.5f * dt * dx[2];
        a.kx[p * 3] = dx[0]; a.kx[p * 3 + 1] = dx[1]; a.kx[p * 3 + 2] = dx[2];
        a.kl[p] = klv;
      } else if (m == 1) {
        o0 = xc0 + 0.5f * dt * dx[0]; o1 = xc1 + 0.5f * dt * dx[1]; o2 = xc2 + 0.5f * dt * dx[2];
        a.kx[p * 3] += 2.f * dx[0]; a.kx[p * 3 + 1] += 2.f * dx[1]; a.kx[p * 3 + 2] += 2.f * dx[2];
        a.kl[p] += 2.f * klv;
      } else if (m == 2) {
        o0 = xc0 + dt * dx[0]; o1 = xc1 + dt * dx[1]; o2 = xc2 + dt * dx[2];
        a.kx[p * 3] += 2.f * dx[0]; a.kx[p * 3 + 1] += 2.f * dx[1]; a.kx[p * 3 + 2] += 2.f * dx[2];
        a.kl[p] += 2.f * klv;
      } else {
        float sc = dt * (1.f / 6.f);
        o0 = xc0 + sc * (a.kx[p * 3] + dx[0]);
        o1 = xc1 + sc * (a.kx[p * 3 + 1] + dx[1]);
        o2 = xc2 + sc * (a.kx[p * 3 + 2] + dx[2]);
        a.x_cur[p * 3] = o0; a.x_cur[p * 3 + 1] = o1; a.x_cur[p * 3 + 2] = o2;
        a.lp_state[p] += sc * (a.kl[p] + klv);
      }
    }
    xe[tid][0] = o0; xe[tid][1] = o1; xe[tid][2] = o2;
  }
  __syncthreads();

  float t = a.ts_cur * dt;

  // ---- layer0: 32 threads per point, 16 cols each -> H1 (fp8) in LDS
  {
    float x0 = xe[pl0][0], x1 = xe[pl0][1], x2 = xe[pl0][2];
    u16x8 gcv[4] = {gc0, gc1, gc2, gc3};
    #pragma unroll
    for (int cc = 0; cc < 4; ++cc) {
      u16x8 v = gcv[cc];
      unsigned ph = 0, p0v = 0, p1v = 0, p2v = 0;
      #pragma unroll
      for (int k = 0; k < 4; ++k) {
        int o = base_o + cc * 4 + k;
        f32x4 e = *(const f32x4*)(a.E0 + (size_t)o * 8);
        f32x2 e2 = *(const f32x2*)(a.E0 + (size_t)o * 8 + 4);
        float u = fmaf(e[0], x0, fmaf(e[1], x1, e[2] * x2)) + e[3];
        float gate = sigf(bf2f(v[2 * k]) + t * e2[0]);
        float bias = bf2f(v[2 * k + 1]) + t * e2[1];
        float z = fmaf(u, gate, bias);
        float h = fast_tanh(z);
        float wm = (1.f - h * h) * gate * TS;
        ph  |= ((unsigned)f2f8(h)) << (8 * k);
        p0v |= ((unsigned)f2f8(wm * e[0])) << (8 * k);
        p1v |= ((unsigned)f2f8(wm * e[1])) << (8 * k);
        p2v |= ((unsigned)f2f8(wm * e[2])) << (8 * k);
      }
      size_t hb = (size_t)(pl0 * 4) * HSTRB + base_o + cc * 4;
      *(unsigned*)(Hs + hb) = ph;
      *(unsigned*)(Hs + hb + HSTRB) = p0v;
      *(unsigned*)(Hs + hb + 2 * HSTRB) = p1v;
      *(unsigned*)(Hs + hb + 3 * HSTRB) = p2v;
    }
  }

  // ---- prefetch epilogue-1 gate dwords (hidden behind GEMM1)
  unsigned g1v[4][4];
  #pragma unroll
  for (int j = 0; j < 4; ++j)
    #pragma unroll
    for (int i = 0; i < 4; ++i) {
      int n = n0 + j * 16 + lr;
      int p = p0 + i * 4 + quad;
      g1v[j][i] = *(const unsigned*)(a.GBi1 + (size_t)p * 1024 + 2 * n);
    }
  __syncthreads();   // H1 visible; W1 chunk0 drained

  // ---- layer1 GEMM: W chunks via LDS dbuf, one barrier per chunk
  f32x4 acc[4][4];
  #pragma unroll
  for (int i = 0; i < 4; ++i)
    #pragma unroll
    for (int j = 0; j < 4; ++j)
      #pragma unroll
      for (int r = 0; r < 4; ++r) acc[i][j][r] = 0.f;
  {
    #pragma unroll 1
    for (int c = 0; c < 16; ++c) {
      int cur = c & 1;
      // prefetch next chunk (or GEMM2's chunk 0 on the tail) into the other buffer
      const u8* nsrc = (c < 15) ? (a.W1s + (size_t)(c + 1) * 16384) : a.W2s;
      gl2lds16b(nsrc + tid * 16, WsL + ((cur ^ 1) * 16384) + tid * 16);
      gl2lds16b(nsrc + 8192 + tid * 16, WsL + ((cur ^ 1) * 16384) + 8192 + tid * 16);
      int k0 = c * 32;
      i64 bf[4], af[4];
      #pragma unroll
      for (int j = 0; j < 4; ++j)
        bf[j] = *(const i64*)(WsL + cur * 16384 + (size_t)(n0 + j * 16 + lr) * 32 + quad * 8);
      #pragma unroll
      for (int i = 0; i < 4; ++i)
        af[i] = *(const i64*)(Hs + (size_t)(i * 16 + lr) * HSTRB + k0 + quad * 8);
      #pragma unroll
      for (int i = 0; i < 4; ++i)
        #pragma unroll
        for (int j = 0; j < 4; ++j)
          acc[i][j] = __builtin_amdgcn_mfma_f32_16x16x32_fp8_fp8(af[i], bf[j], acc[i][j], 0, 0, 0);
      __syncthreads();
    }
  }

  // ---- epilogue1 -> H2 (fp8) in same LDS (FULLY unrolled)
  #pragma unroll
  for (int j = 0; j < 4; ++j) {
    int n = n0 + j * 16 + lr;
    f32x4 e1 = *(const f32x4*)(a.E1 + (size_t)n * 4);
    #pragma unroll
    for (int i = 0; i < 4; ++i) {
      unsigned d = g1v[j][i];
      float gate = sigf(bf2f((u16)(d & 0xffffu)) + t * e1[1]);
      float bias = bf2f((u16)(d >> 16)) + t * e1[2];
      f32x4 u = acc[i][j];
      float z = fmaf(u[0] + e1[0], gate, bias);
      float h = fast_tanh(z);
      float wmf = (1.f - h * h) * gate;
      int row = i * 16 + quad * 4;
      Hs[(size_t)row * HSTRB + n] = f2f8(h);
      Hs[(size_t)(row + 1) * HSTRB + n] = f2f8(u[1] * wmf);
      Hs[(size_t)(row + 2) * HSTRB + n] = f2f8(u[2] * wmf);
      Hs[(size_t)(row + 3) * HSTRB + n] = f2f8(u[3] * wmf);
    }
  }

  // ---- prefetch epilogue-2 gate dwords (hidden behind GEMM2)
  unsigned g2v[4][4];
  #pragma unroll
  for (int j = 0; j < 4; ++j)
    #pragma unroll
    for (int i = 0; i < 4; ++i) {
      int n = n0 + j * 16 + lr;
      int p = p0 + i * 4 + quad;
      g2v[j][i] = *(const unsigned*)(a.GBi2 + (size_t)p * 1024 + 2 * n);
    }
  __syncthreads();   // H2 visible; W2 chunk0 already staged in buf0

  // ---- layer2 GEMM
  #pragma unroll
  for (int i = 0; i < 4; ++i)
    #pragma unroll
    for (int j = 0; j < 4; ++j)
      #pragma unroll
      for (int r = 0; r < 4; ++r) acc[i][j][r] = 0.f;
  {
    #pragma unroll 1
    for (int c = 0; c < 16; ++c) {
      int cur = c & 1;
      if (c < 15) {
        const u8* nsrc = a.W2s + (size_t)(c + 1) * 16384;
        gl2lds16b(nsrc + tid * 16, WsL + ((cur ^ 1) * 16384) + tid * 16);
        gl2lds16b(nsrc + 8192 + tid * 16, WsL + ((cur ^ 1) * 16384) + 8192 + tid * 16);
      }
      int k0 = c * 32;
      i64 bf[4], af[4];
      #pragma unroll
      for (int j = 0; j < 4; ++j)
        bf[j] = *(const i64*)(WsL + cur * 16384 + (size_t)(n0 + j * 16 + lr) * 32 + quad * 8);
      #pragma unroll
      for (int i = 0; i < 4; ++i)
        af[i] = *(const i64*)(Hs + (size_t)(i * 16 + lr) * HSTRB + k0 + quad * 8);
      #pragma unroll
      for (int i = 0; i < 4; ++i)
        #pragma unroll
        for (int j = 0; j < 4; ++j)
          acc[i][j] = __builtin_amdgcn_mfma_f32_16x16x32_fp8_fp8(af[i], bf[j], acc[i][j], 0, 0, 0);
      __syncthreads();
    }
  }

  // ---- epilogue2: gate/tanh + project onto W3 -> 6 partials per point
  #pragma unroll
  for (int i = 0; i < 4; ++i) {
    float v0 = 0.f, v1 = 0.f, v2 = 0.f, v3 = 0.f, v4 = 0.f, v5 = 0.f;
    int pl = i * 4 + quad;
    #pragma unroll
    for (int j = 0; j < 4; ++j) {
      int n = n0 + j * 16 + lr;
      f32x4 ea = *(const f32x4*)(a.E2 + (size_t)n * 8);
      f32x2 eb = *(const f32x2*)(a.E2 + (size_t)n * 8 + 4);
      unsigned d = g2v[j][i];
      float gate = sigf(bf2f((u16)(d & 0xffffu)) + t * ea[1]);
      float bias = bf2f((u16)(d >> 16)) + t * ea[2];
      f32x4 u = acc[i][j];
      float z = fmaf(u[0] + ea[0], gate, bias);
      float h = fast_tanh(z);
      float wmf = (1.f - h * h) * gate;
      float w30 = ea[3], w31 = eb[0], w32 = eb[1];
      v0 = fmaf(h, w30, v0);
      v1 = fmaf(h, w31, v1);
      v2 = fmaf(h, w32, v2);
      v3 = fmaf(u[1] * wmf, w30, v3);
      v4 = fmaf(u[2] * wmf, w31, v4);
      v5 = fmaf(u[3] * wmf, w32, v5);
    }
    #pragma unroll
    for (int mask = 1; mask <= 8; mask <<= 1) {
      v0 += __shfl_xor(v0, mask);
      v1 += __shfl_xor(v1, mask);
      v2 += __shfl_xor(v2, mask);
      v3 += __shfl_xor(v3, mask);
      v4 += __shfl_xor(v4, mask);
      v5 += __shfl_xor(v5, mask);
    }
    // tangent streams carry TS scale through both GEMMs -> undo here
    float val = (lr == 0) ? v0 : (lr == 1) ? v1 : (lr == 2) ? v2
              : (lr == 3) ? v3 * (1.f / TS) : (lr == 4) ? v4 * (1.f / TS)
              : v5 * (1.f / TS);
    if (lr < 6) part[w][pl][lr] = val;
  }
  __syncthreads();

  if (tid < 96) {
    int pt = tid / 6, d = tid - pt * 6;
    float sum = 0.f;
    #pragma unroll
    for (int ww = 0; ww < 8; ++ww) sum += part[ww][pt][d];
    a.accum6[(size_t)(p0 + pt) * 6 + d] = sum;
  }
}

// ---------------------------------------------------------------- finalize
struct FinArgs {
  const float* sqrtT;
  const float* accum6;
  const float *G3, *B3, *Wg3, *Wb3, *b3;
  float *x_cur, *kx, *kl, *lp_state;
  const float *m2, *v2, *lg2, *be2;
  float* out_x;
};
__global__ void finalize_kernel(FinArgs a) {
  int p = blockIdx.x * 256 + threadIdx.x;
  if (p >= PTS) return;
  float s0 = a.sqrtT[0];
  float dt = s0 * s0 * (1.f / 3.f);
  float tp = 3.f * dt;
  float dx[3], gate[3];
  #pragma unroll
  for (int r = 0; r < 3; ++r) {
    float fr = a.accum6[(size_t)p * 6 + r];
    gate[r] = sigf(a.G3[p * 3 + r] + tp * a.Wg3[r * 65]);
    float bias = a.B3[p * 3 + r] + tp * a.Wb3[r * 65];
    dx[r] = fmaf(fr + a.b3[r], gate[r], bias);
  }
  float klv = -(a.accum6[(size_t)p * 6 + 3] * gate[0] +
                a.accum6[(size_t)p * 6 + 4] * gate[1] +
                a.accum6[(size_t)p * 6 + 5] * gate[2]);
  float sc = dt * (1.f / 6.f);
  #pragma unroll
  for (int r = 0; r < 3; ++r) {
    float xf = a.x_cur[p * 3 + r] + sc * (a.kx[p * 3 + r] + dx[r]);
    a.out_x[p * 3 + r] = (xf - a.m2[r]) * __expf(a.lg2[r]) * rsqrtf(a.v2[r] + BN_EPS) + a.be2[r];
  }
  a.lp_state[p] += sc * (a.kl[p] + klv);
}

__global__ void finish_lp(const float* __restrict__ lp_state,
                          const float* __restrict__ v1, const float* __restrict__ lg1,
                          const float* __restrict__ v2, const float* __restrict__ lg2,
                          float* __restrict__ out) {
  int b = blockIdx.x, tid = threadIdx.x;
  float s = 0.f;
  for (int n = tid; n < 2048; n += 256) s += lp_state[b * 2048 + n];
  __shared__ float red[256];
  red[tid] = s;
  __syncthreads();
  for (int w = 128; w > 0; w >>= 1) {
    if (tid < w) red[tid] += red[tid + w];
    __syncthreads();
  }
  if (tid == 0) {
    float ld = 0.f;
    for (int d = 0; d < 3; ++d) {
      ld += lg1[d] - 0.5f * logf(v1[d] + BN_EPS);
      ld += lg2[d] - 0.5f * logf(v2[d] + BN_EPS);
    }
    out[b] = red[0] - 2048.f * ld;
  }
}

// ---------------------------------------------------------------- launch
extern "C" void kernel_launch(void* const* d_in, const int* in_sizes, int n_in,
                              void* d_out, int out_size, void* d_ws, size_t ws_size,
                              hipStream_t stream) {
  const float* x        = (const float*)d_in[0];
  const float* c        = (const float*)d_in[1];
  const float* bn1_mean = (const float*)d_in[2];
  const float* bn1_var  = (const float*)d_in[3];
  const float* bn1_lg   = (const float*)d_in[4];
  const float* bn1_beta = (const float*)d_in[5];
  const float* bn2_mean = (const float*)d_in[6];
  const float* bn2_var  = (const float*)d_in[7];
  const float* bn2_lg   = (const float*)d_in[8];
  const float* bn2_beta = (const float*)d_in[9];
  const float* sqrtT    = (const float*)d_in[10];
  const float* W0  = (const float*)d_in[11];
  const float* b0  = (const float*)d_in[12];
  const float* Wg0 = (const float*)d_in[13];
  const float* bg0 = (const float*)d_in[14];
  const float* Wb0 = (const float*)d_in[15];
  const float* W1  = (const float*)d_in[16];
  const float* b1  = (const float*)d_in[17];
  const float* Wg1 = (const float*)d_in[18];
  const float* bg1 = (const float*)d_in[19];
  const float* Wb1 = (const float*)d_in[20];
  const float* W2  = (const float*)d_in[21];
  const float* b2  = (const float*)d_in[22];
  const float* Wg2 = (const float*)d_in[23];
  const float* bg2 = (const float*)d_in[24];
  const float* Wb2 = (const float*)d_in[25];
  const float* W3  = (const float*)d_in[26];
  const float* b3  = (const float*)d_in[27];
  const float* Wg3 = (const float*)d_in[28];
  const float* bg3 = (const float*)d_in[29];
  const float* Wb3 = (const float*)d_in[30];

  char* base = (char*)d_ws;
  size_t off = 0;
  auto alloc = [&](size_t bytes) -> void* {
    void* pp = base + off;
    off += (bytes + 255) & ~(size_t)255;
    return pp;
  };
  u8* W1s = (u8*)alloc((size_t)512 * 512);
  u8* W2s = (u8*)alloc((size_t)512 * 512);
  u16* cb  = (u16*)alloc((size_t)PTS * 64 * 2);
  u16* Wpack = (u16*)alloc((size_t)6 * 512 * 64 * 2);
  float* bias_pack = (float*)alloc((size_t)3072 * 4);
  u16* GBi = (u16*)alloc((size_t)3 * PTS * 1024 * 2);
  const size_t SZi = (size_t)PTS * 1024;
  u16* GBi0 = GBi;
  u16* GBi1 = GBi + SZi;
  u16* GBi2 = GBi + 2 * SZi;
  float* G3f = (float*)alloc((size_t)PTS * 3 * 4);
  float* B3f = (float*)alloc((size_t)PTS * 3 * 4);
  float* E0 = (float*)alloc((size_t)512 * 8 * 4);
  float* E1 = (float*)alloc((size_t)512 * 4 * 4);
  float* E2 = (float*)alloc((size_t)512 * 8 * 4);
  float* accum6   = (float*)alloc((size_t)PTS * 6 * 4);
  float* x_cur    = (float*)alloc((size_t)PTS * 3 * 4);
  float* kx       = (float*)alloc((size_t)PTS * 3 * 4);
  float* kl       = (float*)alloc((size_t)PTS * 4);
  float* lp_state = (float*)alloc((size_t)PTS * 4);
  (void)ws_size; (void)in_sizes; (void)n_in; (void)out_size;

  PrepArgs pa{W1, W2, W1s, W2s, c, cb, Wg0, Wg1, Wg2, Wb0, Wb1, Wb2,
              bg0, bg1, bg2, Wpack, bias_pack, x, bn1_mean, bn1_var,
              bn1_lg, bn1_beta, x_cur, lp_state, Wg3, bg3, Wb3, G3f, B3f,
              W0, b0, b1, b2, W3, E0, E1, E2};
  prep_kernel<<<2048, 256, 0, stream>>>(pa);

  GatesGemmArgs gg{cb, Wpack, bias_pack, GBi};
  gates_gemm<<<dim3(64, 24), 256, 0, stream>>>(gg);

  auto ts_of = [](int s) -> float {
    static const float frac[4] = {0.f, 0.5f, 0.5f, 1.f};
    return (float)(s >> 2) + frac[s & 3];
  };

  for (int s = 0; s < 12; ++s) {
    StageArgs sa{sqrtT, (s == 0) ? 0.f : ts_of(s - 1), ts_of(s),
                 (s == 0) ? -1 : ((s - 1) & 3), accum6,
                 G3f, B3f, Wg3, Wb3, b3, x_cur, kx, kl, lp_state,
                 GBi0, GBi1, GBi2, E0, E1, E2, W1s, W2s};
    stage_kernel<<<PTS / 16, 512, 0, stream>>>(sa);
  }

  FinArgs fa{sqrtT, accum6, G3f, B3f, Wg3, Wb3, b3, x_cur, kx, kl,
             lp_state, bn2_mean, bn2_var, bn2_lg, bn2_beta, (float*)d_out};
  finalize_kernel<<<32, 256, 0, stream>>>(fa);
  finish_lp<<<4, 256, 0, stream>>>(lp_state, bn1_var, bn1_lg, bn2_var, bn2_lg,
                                   (float*)d_out + PTS * 3);
}

// Round 13
// 733.372 us; speedup vs baseline: 2.5485x; 1.0814x over previous
//
#include <hip/hip_runtime.h>
#include <hip/hip_fp8.h>

#define PTS 8192          // B*N = 4*2048 points
#define HDIM 512
#define BN_EPS 1e-4f
#define HSTRB 528         // LDS row stride in BYTES (fp8 cols)
#define TS 256.0f         // tangent-stream scale (keeps JVP streams out of e4m3 subnormals)

typedef unsigned short u16;
typedef unsigned char u8;
typedef long long i64;
typedef u16 u16x8 __attribute__((ext_vector_type(8)));
typedef short s16x8 __attribute__((ext_vector_type(8)));
typedef float f32x4 __attribute__((ext_vector_type(4)));
typedef float f32x2 __attribute__((ext_vector_type(2)));

__device__ __forceinline__ float bf2f(u16 u) {
  unsigned x = ((unsigned)u) << 16;
  return __builtin_bit_cast(float, x);
}
__device__ __forceinline__ u16 f2bf(float f) {
  unsigned x = __builtin_bit_cast(unsigned, f);
  x += 0x7fffu + ((x >> 16) & 1u);
  return (u16)(x >> 16);
}
// native HW fp8 convert (v_cvt_pk_fp8_f32; OCP e4m3 on gfx950)
__device__ __forceinline__ u8 f2f8(float x) {
  int v = __builtin_amdgcn_cvt_pk_fp8_f32(x, x, 0, false);
  return (u8)(v & 0xff);
}
__device__ __forceinline__ unsigned pk4_f8(float a, float b, float c, float d) {
  int v = __builtin_amdgcn_cvt_pk_fp8_f32(a, b, 0, false);
  v = __builtin_amdgcn_cvt_pk_fp8_f32(c, d, v, true);
  return (unsigned)v;
}
__device__ __forceinline__ float sigf(float x) {
  return __builtin_amdgcn_rcpf(1.f + __expf(-x));
}
__device__ __forceinline__ float fast_tanh(float x) {
  float e = __expf(2.f * x);
  return 1.f - 2.f * __builtin_amdgcn_rcpf(e + 1.f);
}
__device__ __forceinline__ void gl2lds16(const u16* g, u16* l) {
  __builtin_amdgcn_global_load_lds(
      (const __attribute__((address_space(1))) void*)g,
      (__attribute__((address_space(3))) void*)l, 16, 0, 0);
}
__device__ __forceinline__ void gl2lds16b(const u8* g, u8* l) {
  __builtin_amdgcn_global_load_lds(
      (const __attribute__((address_space(1))) void*)g,
      (__attribute__((address_space(3))) void*)l, 16, 0, 0);
}

// ---------------------------------------------------------------- prep
struct PrepArgs {
  const float *W1, *W2;
  u8 *W1s, *W2s;       // fp8 e4m3, frag-order: [16 chunks][8 waves][4 j][64 lanes][8 B]
  const float* c;
  u16* cb;
  const float *Wg0, *Wg1, *Wg2, *Wb0, *Wb1, *Wb2;
  const float *bg0, *bg1, *bg2;
  u16* Wpack;          // [6*512][64] bf16
  float* bias_pack;    // [3072]
  const float *x, *m1, *v1, *lg1, *be1;
  float *x_cur, *lp_state;
  const float *Wg3, *bg3, *Wb3;
  float *G3, *B3;
  const float *W0, *b0, *b1, *b2, *W3;
  float *E0, *E1, *E2;   // packed epilogue params
};
__global__ void prep_kernel(PrepArgs a) {
  int i = blockIdx.x * 256 + threadIdx.x;   // 0 .. 524287
  if (i < 512 * 512) {
    int n = i >> 9, k = i & 511;
    int c = k >> 5, kin = k & 31, q = kin >> 3, b = kin & 7;
    int w = n >> 6, nin = n & 63, j = nin >> 4, lr = nin & 15;
    size_t d = ((((size_t)(c * 8 + w) * 4 + j) * 64) + (q * 16 + lr)) * 8 + b;
    a.W1s[d] = f2f8(a.W1[i]);
    a.W2s[d] = f2f8(a.W2[i]);
  }
  if (i < PTS * 64) a.cb[i] = f2bf(a.c[i]);
  if (i < 6 * 512 * 64) {
    int sec = i >> 15;
    int within = i & 32767;
    int o = within >> 6, k = within & 63;
    const float* src[6] = {a.Wg0, a.Wg1, a.Wg2, a.Wb0, a.Wb1, a.Wb2};
    a.Wpack[i] = f2bf(src[sec][o * 65 + 1 + k]);
  }
  if (i < 3072) {
    int sec = i >> 9, o = i & 511;
    const float* bgl[3] = {a.bg0, a.bg1, a.bg2};
    a.bias_pack[i] = (sec < 3) ? bgl[sec][o] : 0.f;
  }
  if (i < 512) {
    int o = i;
    a.E0[o * 8 + 0] = a.W0[o * 3];
    a.E0[o * 8 + 1] = a.W0[o * 3 + 1];
    a.E0[o * 8 + 2] = a.W0[o * 3 + 2];
    a.E0[o * 8 + 3] = a.b0[o];
    a.E0[o * 8 + 4] = a.Wg0[o * 65];
    a.E0[o * 8 + 5] = a.Wb0[o * 65];
    a.E0[o * 8 + 6] = 0.f; a.E0[o * 8 + 7] = 0.f;
    a.E1[o * 4 + 0] = a.b1[o];
    a.E1[o * 4 + 1] = a.Wg1[o * 65];
    a.E1[o * 4 + 2] = a.Wb1[o * 65];
    a.E1[o * 4 + 3] = 0.f;
    a.E2[o * 8 + 0] = a.b2[o];
    a.E2[o * 8 + 1] = a.Wg2[o * 65];
    a.E2[o * 8 + 2] = a.Wb2[o * 65];
    a.E2[o * 8 + 3] = a.W3[o];
    a.E2[o * 8 + 4] = a.W3[512 + o];
    a.E2[o * 8 + 5] = a.W3[1024 + o];
    a.E2[o * 8 + 6] = 0.f; a.E2[o * 8 + 7] = 0.f;
  }
  if (i < PTS * 3) {
    int d = i % 3;
    a.x_cur[i] = (a.x[i] - a.m1[d]) * __expf(a.lg1[d]) * rsqrtf(a.v1[d] + BN_EPS) + a.be1[d];
  }
  if (i < PTS) a.lp_state[i] = 0.f;
  {
    int lane = threadIdx.x & 63;
    int p = (blockIdx.x * 256 + threadIdx.x) >> 6;   // 0..8191
    float cv = a.c[(size_t)p * 64 + lane];
    float ag[3], ab[3];
    #pragma unroll
    for (int o = 0; o < 3; ++o) {
      ag[o] = cv * a.Wg3[o * 65 + 1 + lane];
      ab[o] = cv * a.Wb3[o * 65 + 1 + lane];
    }
    #pragma unroll
    for (int off = 32; off > 0; off >>= 1) {
      #pragma unroll
      for (int o = 0; o < 3; ++o) {
        ag[o] += __shfl_xor(ag[o], off);
        ab[o] += __shfl_xor(ab[o], off);
      }
    }
    if (lane == 0) {
      #pragma unroll
      for (int o = 0; o < 3; ++o) {
        a.G3[p * 3 + o] = ag[o] + a.bg3[o];
        a.B3[p * 3 + o] = ab[o];
      }
    }
  }
}

// ---------------------------------------------------------------- gates GEMM (bf16, proven)
struct GatesGemmArgs {
  const u16 *A, *W;
  const float* bias;
  u16* GBi;                // [3][8192][1024] interleaved
};
__global__ __launch_bounds__(256) void gates_gemm(GatesGemmArgs a) {
  __shared__ u16 As[128 * 32];
  __shared__ u16 Bs[128 * 32];
  int tid = threadIdx.x;
  int m0 = blockIdx.x * 128, n0 = blockIdx.y * 128;
  int wave = tid >> 6, lane = tid & 63;
  int wm = (wave & 1) * 64, wn = (wave >> 1) * 64;
  int lr = lane & 15, quad = lane >> 4;

  int rowS = tid >> 2, colS = (tid & 3) * 8;
  const u16* gA0 = a.A + (size_t)(m0 + rowS) * 64 + colS;
  const u16* gB0 = a.W + (size_t)(n0 + rowS) * 64 + colS;
  u16* sA0 = &As[tid * 8];
  u16* sA1 = &As[2048 + tid * 8];
  u16* sB0 = &Bs[tid * 8];
  u16* sB1 = &Bs[2048 + tid * 8];

  f32x4 acc[4][4];
  #pragma unroll
  for (int i = 0; i < 4; ++i)
    #pragma unroll
    for (int j = 0; j < 4; ++j)
      #pragma unroll
      for (int r = 0; r < 4; ++r) acc[i][j][r] = 0.f;

  for (int k0 = 0; k0 < 64; k0 += 32) {
    if (k0) __syncthreads();
    gl2lds16(gA0 + k0, sA0);
    gl2lds16(gA0 + (size_t)64 * 64 + k0, sA1);
    gl2lds16(gB0 + k0, sB0);
    gl2lds16(gB0 + (size_t)64 * 64 + k0, sB1);
    __syncthreads();
    s16x8 af[4], bfr[4];
    #pragma unroll
    for (int i = 0; i < 4; ++i)
      af[i] = *(const s16x8*)&As[(wm + i * 16 + lr) * 32 + quad * 8];
    #pragma unroll
    for (int j = 0; j < 4; ++j)
      bfr[j] = *(const s16x8*)&Bs[(wn + j * 16 + lr) * 32 + quad * 8];
    #pragma unroll
    for (int i = 0; i < 4; ++i)
      #pragma unroll
      for (int j = 0; j < 4; ++j)
        acc[i][j] = __builtin_amdgcn_mfma_f32_16x16x32_bf16(af[i], bfr[j], acc[i][j], 0, 0, 0);
  }

  #pragma unroll
  for (int j = 0; j < 4; ++j) {
    int n = n0 + wn + j * 16 + lr;
    int sec = n >> 9, col = n & 511;
    int l = (sec < 3) ? sec : sec - 3;
    int off = col * 2 + ((sec < 3) ? 0 : 1);
    float bv = a.bias[n];
    u16* outp = a.GBi + (size_t)l * PTS * 1024 + off;
    #pragma unroll
    for (int i = 0; i < 4; ++i) {
      int mrow = m0 + wm + i * 16 + quad * 4;
      #pragma unroll
      for (int r = 0; r < 4; ++r)
        outp[(size_t)(mrow + r) * 1024] = f2bf(acc[i][j][r] + bv);
    }
  }
}

// ---------------------------------------------------------------- per-stage kernel (fp8, W via LDS)
// 512 blocks x 512 threads (8 waves); block owns 16 points (64 m-rows).
// W streamed global->LDS in FRAG ORDER (lane-contiguous reads, no 4-way conflicts),
// double-buffered gl2lds, one barrier per 32-k chunk.
struct StageArgs {
  const float* sqrtT;
  float ts_prev, ts_cur;
  int mode_prev;             // -1 none, 0,1,2 stage folds, 3 step-end fold
  float* accum6;             // [PTS][6]
  const float *G3, *B3, *Wg3, *Wb3, *b3;
  float *x_cur, *kx, *kl, *lp_state;
  const u16 *GBi0, *GBi1, *GBi2;   // interleaved gate tables [PTS][1024]
  const float *E0, *E1, *E2;       // packed params
  const u8 *W1s, *W2s;             // fp8 weights frag-order [16][8][4][64][8]
};

__global__ __launch_bounds__(512, 4) void stage_kernel(StageArgs a) {
  __shared__ __align__(16) u8 Hs[64 * HSTRB];     // 33.8 KB (fp8 activations)
  __shared__ __align__(16) u8 WsL[2 * 16384];     // 32 KB W chunk double-buffer
  __shared__ float xe[16][3];
  __shared__ float part[8][16][6];
  int tid = threadIdx.x;
  int w = tid >> 6, lane = tid & 63, lr = lane & 15, quad = lane >> 4;
  int n0 = w * 64;
  int p0 = blockIdx.x * 16;
  float s0 = a.sqrtT[0];
  float dt = s0 * s0 * (1.f / 3.f);

  // ---- stage W1 chunk 0 into buf0 immediately (drained by pre-GEMM1 barrier)
  gl2lds16b(a.W1s + tid * 16, WsL + tid * 16);
  gl2lds16b(a.W1s + 8192 + tid * 16, WsL + 8192 + tid * 16);

  // ---- issue L0 gate loads EARLY (independent of fold)
  int pl0 = tid >> 5;
  int base_o = (tid & 31) * 16;
  const u16* g0row = a.GBi0 + (size_t)(p0 + pl0) * 1024 + 2 * base_o;
  u16x8 gc0 = *(const u16x8*)(g0row);
  u16x8 gc1 = *(const u16x8*)(g0row + 8);
  u16x8 gc2 = *(const u16x8*)(g0row + 16);
  u16x8 gc3 = *(const u16x8*)(g0row + 24);

  // ---- fold previous stage (thread per point)
  if (tid < 16) {
    int p = p0 + tid;
    float xc0 = a.x_cur[p * 3], xc1 = a.x_cur[p * 3 + 1], xc2 = a.x_cur[p * 3 + 2];
    float o0 = xc0, o1 = xc1, o2 = xc2;
    if (a.mode_prev >= 0) {
      float tp = a.ts_prev * dt;
      float dx[3], gate[3];
      #pragma unroll
      for (int r = 0; r < 3; ++r) {
        float fr = a.accum6[(size_t)p * 6 + r];
        gate[r] = sigf(a.G3[p * 3 + r] + tp * a.Wg3[r * 65]);
        float bias = a.B3[p * 3 + r] + tp * a.Wb3[r * 65];
        dx[r] = fmaf(fr + a.b3[r], gate[r], bias);
      }
      float klv = -(a.accum6[(size_t)p * 6 + 3] * gate[0] +
                    a.accum6[(size_t)p * 6 + 4] * gate[1] +
                    a.accum6[(size_t)p * 6 + 5] * gate[2]);
      int m = a.mode_prev;
      if (m == 0) {
        o0 = xc0 + 0.5f * dt * dx[0]; o1 = xc1 + 0.5f * dt * dx[1]; o2 = xc2 + 0.5f * dt * dx[2];
        a.kx[p * 3] = dx[0]; a.kx[p * 3 + 1] = dx[1]; a.kx[p * 3 + 2] = dx[2];
        a.kl[p] = klv;
      } else if (m == 1) {
        o0 = xc0 + 0.5f * dt * dx[0]; o1 = xc1 + 0.5f * dt * dx[1]; o2 = xc2 + 0.5f * dt * dx[2];
        a.kx[p * 3] += 2.f * dx[0]; a.kx[p * 3 + 1] += 2.f * dx[1]; a.kx[p * 3 + 2] += 2.f * dx[2];
        a.kl[p] += 2.f * klv;
      } else if (m == 2) {
        o0 = xc0 + dt * dx[0]; o1 = xc1 + dt * dx[1]; o2 = xc2 + dt * dx[2];
        a.kx[p * 3] += 2.f * dx[0]; a.kx[p * 3 + 1] += 2.f * dx[1]; a.kx[p * 3 + 2] += 2.f * dx[2];
        a.kl[p] += 2.f * klv;
      } else {
        float sc = dt * (1.f / 6.f);
        o0 = xc0 + sc * (a.kx[p * 3] + dx[0]);
        o1 = xc1 + sc * (a.kx[p * 3 + 1] + dx[1]);
        o2 = xc2 + sc * (a.kx[p * 3 + 2] + dx[2]);
        a.x_cur[p * 3] = o0; a.x_cur[p * 3 + 1] = o1; a.x_cur[p * 3 + 2] = o2;
        a.lp_state[p] += sc * (a.kl[p] + klv);
      }
    }
    xe[tid][0] = o0; xe[tid][1] = o1; xe[tid][2] = o2;
  }
  __syncthreads();

  float t = a.ts_cur * dt;

  // ---- layer0: 32 threads per point, 16 cols each -> H1 (fp8) in LDS
  {
    float x0 = xe[pl0][0], x1 = xe[pl0][1], x2 = xe[pl0][2];
    u16x8 gcv[4] = {gc0, gc1, gc2, gc3};
    #pragma unroll
    for (int cc = 0; cc < 4; ++cc) {
      u16x8 v = gcv[cc];
      float hk[4], d0k[4], d1k[4], d2k[4];
      #pragma unroll
      for (int k = 0; k < 4; ++k) {
        int o = base_o + cc * 4 + k;
        f32x4 e = *(const f32x4*)(a.E0 + (size_t)o * 8);
        f32x2 e2 = *(const f32x2*)(a.E0 + (size_t)o * 8 + 4);
        float u = fmaf(e[0], x0, fmaf(e[1], x1, e[2] * x2)) + e[3];
        float gate = sigf(bf2f(v[2 * k]) + t * e2[0]);
        float bias = bf2f(v[2 * k + 1]) + t * e2[1];
        float z = fmaf(u, gate, bias);
        float h = fast_tanh(z);
        float wm = (1.f - h * h) * gate * TS;
        hk[k] = h;
        d0k[k] = wm * e[0];
        d1k[k] = wm * e[1];
        d2k[k] = wm * e[2];
      }
      size_t hb = (size_t)(pl0 * 4) * HSTRB + base_o + cc * 4;
      *(unsigned*)(Hs + hb) = pk4_f8(hk[0], hk[1], hk[2], hk[3]);
      *(unsigned*)(Hs + hb + HSTRB) = pk4_f8(d0k[0], d0k[1], d0k[2], d0k[3]);
      *(unsigned*)(Hs + hb + 2 * HSTRB) = pk4_f8(d1k[0], d1k[1], d1k[2], d1k[3]);
      *(unsigned*)(Hs + hb + 3 * HSTRB) = pk4_f8(d2k[0], d2k[1], d2k[2], d2k[3]);
    }
  }

  // ---- prefetch epilogue-1 gate dwords (hidden behind GEMM1)
  unsigned g1v[4][4];
  #pragma unroll
  for (int j = 0; j < 4; ++j)
    #pragma unroll
    for (int i = 0; i < 4; ++i) {
      int n = n0 + j * 16 + lr;
      int p = p0 + i * 4 + quad;
      g1v[j][i] = *(const unsigned*)(a.GBi1 + (size_t)p * 1024 + 2 * n);
    }
  __syncthreads();   // H1 visible; W1 chunk0 drained

  // ---- layer1 GEMM: W chunks via LDS dbuf, one barrier per chunk
  f32x4 acc[4][4];
  #pragma unroll
  for (int i = 0; i < 4; ++i)
    #pragma unroll
    for (int j = 0; j < 4; ++j)
      #pragma unroll
      for (int r = 0; r < 4; ++r) acc[i][j][r] = 0.f;
  {
    #pragma unroll 1
    for (int c = 0; c < 16; ++c) {
      int cur = c & 1;
      // prefetch next chunk (or GEMM2's chunk 0 on the tail) into the other buffer
      const u8* nsrc = (c < 15) ? (a.W1s + (size_t)(c + 1) * 16384) : a.W2s;
      gl2lds16b(nsrc + tid * 16, WsL + ((cur ^ 1) * 16384) + tid * 16);
      gl2lds16b(nsrc + 8192 + tid * 16, WsL + ((cur ^ 1) * 16384) + 8192 + tid * 16);
      int k0 = c * 32;
      i64 bf[4], af[4];
      #pragma unroll
      for (int j = 0; j < 4; ++j)
        bf[j] = *(const i64*)(WsL + cur * 16384 + ((size_t)(w * 4 + j) * 64 + lane) * 8);
      #pragma unroll
      for (int i = 0; i < 4; ++i)
        af[i] = *(const i64*)(Hs + (size_t)(i * 16 + lr) * HSTRB + k0 + quad * 8);
      #pragma unroll
      for (int i = 0; i < 4; ++i)
        #pragma unroll
        for (int j = 0; j < 4; ++j)
          acc[i][j] = __builtin_amdgcn_mfma_f32_16x16x32_fp8_fp8(af[i], bf[j], acc[i][j], 0, 0, 0);
      __syncthreads();
    }
  }

  // ---- epilogue1 -> H2 (fp8) in same LDS (FULLY unrolled)
  #pragma unroll
  for (int j = 0; j < 4; ++j) {
    int n = n0 + j * 16 + lr;
    f32x4 e1 = *(const f32x4*)(a.E1 + (size_t)n * 4);
    #pragma unroll
    for (int i = 0; i < 4; ++i) {
      unsigned d = g1v[j][i];
      float gate = sigf(bf2f((u16)(d & 0xffffu)) + t * e1[1]);
      float bias = bf2f((u16)(d >> 16)) + t * e1[2];
      f32x4 u = acc[i][j];
      float z = fmaf(u[0] + e1[0], gate, bias);
      float h = fast_tanh(z);
      float wmf = (1.f - h * h) * gate;
      int row = i * 16 + quad * 4;
      Hs[(size_t)row * HSTRB + n] = f2f8(h);
      Hs[(size_t)(row + 1) * HSTRB + n] = f2f8(u[1] * wmf);
      Hs[(size_t)(row + 2) * HSTRB + n] = f2f8(u[2] * wmf);
      Hs[(size_t)(row + 3) * HSTRB + n] = f2f8(u[3] * wmf);
    }
  }

  // ---- prefetch epilogue-2 gate dwords (hidden behind GEMM2)
  unsigned g2v[4][4];
  #pragma unroll
  for (int j = 0; j < 4; ++j)
    #pragma unroll
    for (int i = 0; i < 4; ++i) {
      int n = n0 + j * 16 + lr;
      int p = p0 + i * 4 + quad;
      g2v[j][i] = *(const unsigned*)(a.GBi2 + (size_t)p * 1024 + 2 * n);
    }
  __syncthreads();   // H2 visible; W2 chunk0 already staged in buf0

  // ---- layer2 GEMM
  #pragma unroll
  for (int i = 0; i < 4; ++i)
    #pragma unroll
    for (int j = 0; j < 4; ++j)
      #pragma unroll
      for (int r = 0; r < 4; ++r) acc[i][j][r] = 0.f;
  {
    #pragma unroll 1
    for (int c = 0; c < 16; ++c) {
      int cur = c & 1;
      if (c < 15) {
        const u8* nsrc = a.W2s + (size_t)(c + 1) * 16384;
        gl2lds16b(nsrc + tid * 16, WsL + ((cur ^ 1) * 16384) + tid * 16);
        gl2lds16b(nsrc + 8192 + tid * 16, WsL + ((cur ^ 1) * 16384) + 8192 + tid * 16);
      }
      int k0 = c * 32;
      i64 bf[4], af[4];
      #pragma unroll
      for (int j = 0; j < 4; ++j)
        bf[j] = *(const i64*)(WsL + cur * 16384 + ((size_t)(w * 4 + j) * 64 + lane) * 8);
      #pragma unroll
      for (int i = 0; i < 4; ++i)
        af[i] = *(const i64*)(Hs + (size_t)(i * 16 + lr) * HSTRB + k0 + quad * 8);
      #pragma unroll
      for (int i = 0; i < 4; ++i)
        #pragma unroll
        for (int j = 0; j < 4; ++j)
          acc[i][j] = __builtin_amdgcn_mfma_f32_16x16x32_fp8_fp8(af[i], bf[j], acc[i][j], 0, 0, 0);
      __syncthreads();
    }
  }

  // ---- epilogue2: gate/tanh + project onto W3 -> 6 partials per point
  #pragma unroll
  for (int i = 0; i < 4; ++i) {
    float v0 = 0.f, v1 = 0.f, v2 = 0.f, v3 = 0.f, v4 = 0.f, v5 = 0.f;
    int pl = i * 4 + quad;
    #pragma unroll
    for (int j = 0; j < 4; ++j) {
      int n = n0 + j * 16 + lr;
      f32x4 ea = *(const f32x4*)(a.E2 + (size_t)n * 8);
      f32x2 eb = *(const f32x2*)(a.E2 + (size_t)n * 8 + 4);
      unsigned d = g2v[j][i];
      float gate = sigf(bf2f((u16)(d & 0xffffu)) + t * ea[1]);
      float bias = bf2f((u16)(d >> 16)) + t * ea[2];
      f32x4 u = acc[i][j];
      float z = fmaf(u[0] + ea[0], gate, bias);
      float h = fast_tanh(z);
      float wmf = (1.f - h * h) * gate;
      float w30 = ea[3], w31 = eb[0], w32 = eb[1];
      v0 = fmaf(h, w30, v0);
      v1 = fmaf(h, w31, v1);
      v2 = fmaf(h, w32, v2);
      v3 = fmaf(u[1] * wmf, w30, v3);
      v4 = fmaf(u[2] * wmf, w31, v4);
      v5 = fmaf(u[3] * wmf, w32, v5);
    }
    #pragma unroll
    for (int mask = 1; mask <= 8; mask <<= 1) {
      v0 += __shfl_xor(v0, mask);
      v1 += __shfl_xor(v1, mask);
      v2 += __shfl_xor(v2, mask);
      v3 += __shfl_xor(v3, mask);
      v4 += __shfl_xor(v4, mask);
      v5 += __shfl_xor(v5, mask);
    }
    // tangent streams carry TS scale through both GEMMs -> undo here
    float val = (lr == 0) ? v0 : (lr == 1) ? v1 : (lr == 2) ? v2
              : (lr == 3) ? v3 * (1.f / TS) : (lr == 4) ? v4 * (1.f / TS)
              : v5 * (1.f / TS);
    if (lr < 6) part[w][pl][lr] = val;
  }
  __syncthreads();

  if (tid < 96) {
    int pt = tid / 6, d = tid - pt * 6;
    float sum = 0.f;
    #pragma unroll
    for (int ww = 0; ww < 8; ++ww) sum += part[ww][pt][d];
    a.accum6[(size_t)(p0 + pt) * 6 + d] = sum;
  }
}

// ---------------------------------------------------------------- finalize
struct FinArgs {
  const float* sqrtT;
  const float* accum6;
  const float *G3, *B3, *Wg3, *Wb3, *b3;
  float *x_cur, *kx, *kl, *lp_state;
  const float *m2, *v2, *lg2, *be2;
  float* out_x;
};
__global__ void finalize_kernel(FinArgs a) {
  int p = blockIdx.x * 256 + threadIdx.x;
  if (p >= PTS) return;
  float s0 = a.sqrtT[0];
  float dt = s0 * s0 * (1.f / 3.f);
  float tp = 3.f * dt;
  float dx[3], gate[3];
  #pragma unroll
  for (int r = 0; r < 3; ++r) {
    float fr = a.accum6[(size_t)p * 6 + r];
    gate[r] = sigf(a.G3[p * 3 + r] + tp * a.Wg3[r * 65]);
    float bias = a.B3[p * 3 + r] + tp * a.Wb3[r * 65];
    dx[r] = fmaf(fr + a.b3[r], gate[r], bias);
  }
  float klv = -(a.accum6[(size_t)p * 6 + 3] * gate[0] +
                a.accum6[(size_t)p * 6 + 4] * gate[1] +
                a.accum6[(size_t)p * 6 + 5] * gate[2]);
  float sc = dt * (1.f / 6.f);
  #pragma unroll
  for (int r = 0; r < 3; ++r) {
    float xf = a.x_cur[p * 3 + r] + sc * (a.kx[p * 3 + r] + dx[r]);
    a.out_x[p * 3 + r] = (xf - a.m2[r]) * __expf(a.lg2[r]) * rsqrtf(a.v2[r] + BN_EPS) + a.be2[r];
  }
  a.lp_state[p] += sc * (a.kl[p] + klv);
}

__global__ void finish_lp(const float* __restrict__ lp_state,
                          const float* __restrict__ v1, const float* __restrict__ lg1,
                          const float* __restrict__ v2, const float* __restrict__ lg2,
                          float* __restrict__ out) {
  int b = blockIdx.x, tid = threadIdx.x;
  float s = 0.f;
  for (int n = tid; n < 2048; n += 256) s += lp_state[b * 2048 + n];
  __shared__ float red[256];
  red[tid] = s;
  __syncthreads();
  for (int w = 128; w > 0; w >>= 1) {
    if (tid < w) red[tid] += red[tid + w];
    __syncthreads();
  }
  if (tid == 0) {
    float ld = 0.f;
    for (int d = 0; d < 3; ++d) {
      ld += lg1[d] - 0.5f * logf(v1[d] + BN_EPS);
      ld += lg2[d] - 0.5f * logf(v2[d] + BN_EPS);
    }
    out[b] = red[0] - 2048.f * ld;
  }
}

// ---------------------------------------------------------------- launch
extern "C" void kernel_launch(void* const* d_in, const int* in_sizes, int n_in,
                              void* d_out, int out_size, void* d_ws, size_t ws_size,
                              hipStream_t stream) {
  const float* x        = (const float*)d_in[0];
  const float* c        = (const float*)d_in[1];
  const float* bn1_mean = (const float*)d_in[2];
  const float* bn1_var  = (const float*)d_in[3];
  const float* bn1_lg   = (const float*)d_in[4];
  const float* bn1_beta = (const float*)d_in[5];
  const float* bn2_mean = (const float*)d_in[6];
  const float* bn2_var  = (const float*)d_in[7];
  const float* bn2_lg   = (const float*)d_in[8];
  const float* bn2_beta = (const float*)d_in[9];
  const float* sqrtT    = (const float*)d_in[10];
  const float* W0  = (const float*)d_in[11];
  const float* b0  = (const float*)d_in[12];
  const float* Wg0 = (const float*)d_in[13];
  const float* bg0 = (const float*)d_in[14];
  const float* Wb0 = (const float*)d_in[15];
  const float* W1  = (const float*)d_in[16];
  const float* b1  = (const float*)d_in[17];
  const float* Wg1 = (const float*)d_in[18];
  const float* bg1 = (const float*)d_in[19];
  const float* Wb1 = (const float*)d_in[20];
  const float* W2  = (const float*)d_in[21];
  const float* b2  = (const float*)d_in[22];
  const float* Wg2 = (const float*)d_in[23];
  const float* bg2 = (const float*)d_in[24];
  const float* Wb2 = (const float*)d_in[25];
  const float* W3  = (const float*)d_in[26];
  const float* b3  = (const float*)d_in[27];
  const float* Wg3 = (const float*)d_in[28];
  const float* bg3 = (const float*)d_in[29];
  const float* Wb3 = (const float*)d_in[30];

  char* base = (char*)d_ws;
  size_t off = 0;
  auto alloc = [&](size_t bytes) -> void* {
    void* pp = base + off;
    off += (bytes + 255) & ~(size_t)255;
    return pp;
  };
  u8* W1s = (u8*)alloc((size_t)512 * 512);
  u8* W2s = (u8*)alloc((size_t)512 * 512);
  u16* cb  = (u16*)alloc((size_t)PTS * 64 * 2);
  u16* Wpack = (u16*)alloc((size_t)6 * 512 * 64 * 2);
  float* bias_pack = (float*)alloc((size_t)3072 * 4);
  u16* GBi = (u16*)alloc((size_t)3 * PTS * 1024 * 2);
  const size_t SZi = (size_t)PTS * 1024;
  u16* GBi0 = GBi;
  u16* GBi1 = GBi + SZi;
  u16* GBi2 = GBi + 2 * SZi;
  float* G3f = (float*)alloc((size_t)PTS * 3 * 4);
  float* B3f = (float*)alloc((size_t)PTS * 3 * 4);
  float* E0 = (float*)alloc((size_t)512 * 8 * 4);
  float* E1 = (float*)alloc((size_t)512 * 4 * 4);
  float* E2 = (float*)alloc((size_t)512 * 8 * 4);
  float* accum6   = (float*)alloc((size_t)PTS * 6 * 4);
  float* x_cur    = (float*)alloc((size_t)PTS * 3 * 4);
  float* kx       = (float*)alloc((size_t)PTS * 3 * 4);
  float* kl       = (float*)alloc((size_t)PTS * 4);
  float* lp_state = (float*)alloc((size_t)PTS * 4);
  (void)ws_size; (void)in_sizes; (void)n_in; (void)out_size;

  PrepArgs pa{W1, W2, W1s, W2s, c, cb, Wg0, Wg1, Wg2, Wb0, Wb1, Wb2,
              bg0, bg1, bg2, Wpack, bias_pack, x, bn1_mean, bn1_var,
              bn1_lg, bn1_beta, x_cur, lp_state, Wg3, bg3, Wb3, G3f, B3f,
              W0, b0, b1, b2, W3, E0, E1, E2};
  prep_kernel<<<2048, 256, 0, stream>>>(pa);

  GatesGemmArgs gg{cb, Wpack, bias_pack, GBi};
  gates_gemm<<<dim3(64, 24), 256, 0, stream>>>(gg);

  auto ts_of = [](int s) -> float {
    static const float frac[4] = {0.f, 0.5f, 0.5f, 1.f};
    return (float)(s >> 2) + frac[s & 3];
  };

  for (int s = 0; s < 12; ++s) {
    StageArgs sa{sqrtT, (s == 0) ? 0.f : ts_of(s - 1), ts_of(s),
                 (s == 0) ? -1 : ((s - 1) & 3), accum6,
                 G3f, B3f, Wg3, Wb3, b3, x_cur, kx, kl, lp_state,
                 GBi0, GBi1, GBi2, E0, E1, E2, W1s, W2s};
    stage_kernel<<<PTS / 16, 512, 0, stream>>>(sa);
  }

  FinArgs fa{sqrtT, accum6, G3f, B3f, Wg3, Wb3, b3, x_cur, kx, kl,
             lp_state, bn2_mean, bn2_var, bn2_lg, bn2_beta, (float*)d_out};
  finalize_kernel<<<32, 256, 0, stream>>>(fa);
  finish_lp<<<4, 256, 0, stream>>>(lp_state, bn1_var, bn1_lg, bn2_var, bn2_lg,
                                   (float*)d_out + PTS * 3);
}

// Round 14
// 679.393 us; speedup vs baseline: 2.7510x; 1.0795x over previous
//
#include <hip/hip_runtime.h>
#include <hip/hip_fp8.h>

#define PTS 8192          // B*N = 4*2048 points
#define HDIM 512
#define BN_EPS 1e-4f
#define HSTRB 528         // LDS row stride in BYTES (fp8 cols)
#define TS 256.0f         // tangent-stream scale (keeps JVP streams out of e4m3 subnormals)

typedef unsigned short u16;
typedef unsigned char u8;
typedef long long i64;
typedef u16 u16x8 __attribute__((ext_vector_type(8)));
typedef short s16x8 __attribute__((ext_vector_type(8)));
typedef float f32x4 __attribute__((ext_vector_type(4)));
typedef float f32x2 __attribute__((ext_vector_type(2)));

__device__ __forceinline__ float bf2f(u16 u) {
  unsigned x = ((unsigned)u) << 16;
  return __builtin_bit_cast(float, x);
}
__device__ __forceinline__ u16 f2bf(float f) {
  unsigned x = __builtin_bit_cast(unsigned, f);
  x += 0x7fffu + ((x >> 16) & 1u);
  return (u16)(x >> 16);
}
// native HW fp8 convert (v_cvt_pk_fp8_f32; OCP e4m3 on gfx950)
__device__ __forceinline__ u8 f2f8(float x) {
  int v = __builtin_amdgcn_cvt_pk_fp8_f32(x, x, 0, false);
  return (u8)(v & 0xff);
}
__device__ __forceinline__ unsigned pk4_f8(float a, float b, float c, float d) {
  int v = __builtin_amdgcn_cvt_pk_fp8_f32(a, b, 0, false);
  v = __builtin_amdgcn_cvt_pk_fp8_f32(c, d, v, true);
  return (unsigned)v;
}
__device__ __forceinline__ float sigf(float x) {
  return __builtin_amdgcn_rcpf(1.f + __expf(-x));
}
__device__ __forceinline__ float fast_tanh(float x) {
  float e = __expf(2.f * x);
  return 1.f - 2.f * __builtin_amdgcn_rcpf(e + 1.f);
}
__device__ __forceinline__ void gl2lds16(const u16* g, u16* l) {
  __builtin_amdgcn_global_load_lds(
      (const __attribute__((address_space(1))) void*)g,
      (__attribute__((address_space(3))) void*)l, 16, 0, 0);
}

// ---------------------------------------------------------------- prep
struct PrepArgs {
  const float *W1, *W2;
  u8 *W1s, *W2s;       // fp8 e4m3, frag-order: [16 chunks][8 waves][4 j][64 lanes][8 B]
  const float* c;
  u16* cb;
  const float *Wg0, *Wg1, *Wg2, *Wb0, *Wb1, *Wb2;
  const float *bg0, *bg1, *bg2;
  u16* Wpack;          // [6*512][64] bf16
  float* bias_pack;    // [3072]
  const float *x, *m1, *v1, *lg1, *be1;
  float *x_cur, *lp_state;
  const float *Wg3, *bg3, *Wb3;
  float *G3, *B3;
  const float *W0, *b0, *b1, *b2, *W3;
  float *E0, *E1, *E2;   // packed epilogue params
};
__global__ void prep_kernel(PrepArgs a) {
  int i = blockIdx.x * 256 + threadIdx.x;   // 0 .. 524287
  if (i < 512 * 512) {
    int n = i >> 9, k = i & 511;
    int c = k >> 5, kin = k & 31, q = kin >> 3, b = kin & 7;
    int w = n >> 6, nin = n & 63, j = nin >> 4, lr = nin & 15;
    size_t d = ((((size_t)(c * 8 + w) * 4 + j) * 64) + (q * 16 + lr)) * 8 + b;
    a.W1s[d] = f2f8(a.W1[i]);
    a.W2s[d] = f2f8(a.W2[i]);
  }
  if (i < PTS * 64) a.cb[i] = f2bf(a.c[i]);
  if (i < 6 * 512 * 64) {
    int sec = i >> 15;
    int within = i & 32767;
    int o = within >> 6, k = within & 63;
    const float* src[6] = {a.Wg0, a.Wg1, a.Wg2, a.Wb0, a.Wb1, a.Wb2};
    a.Wpack[i] = f2bf(src[sec][o * 65 + 1 + k]);
  }
  if (i < 3072) {
    int sec = i >> 9, o = i & 511;
    const float* bgl[3] = {a.bg0, a.bg1, a.bg2};
    a.bias_pack[i] = (sec < 3) ? bgl[sec][o] : 0.f;
  }
  if (i < 512) {
    int o = i;
    a.E0[o * 8 + 0] = a.W0[o * 3];
    a.E0[o * 8 + 1] = a.W0[o * 3 + 1];
    a.E0[o * 8 + 2] = a.W0[o * 3 + 2];
    a.E0[o * 8 + 3] = a.b0[o];
    a.E0[o * 8 + 4] = a.Wg0[o * 65];
    a.E0[o * 8 + 5] = a.Wb0[o * 65];
    a.E0[o * 8 + 6] = 0.f; a.E0[o * 8 + 7] = 0.f;
    a.E1[o * 4 + 0] = a.b1[o];
    a.E1[o * 4 + 1] = a.Wg1[o * 65];
    a.E1[o * 4 + 2] = a.Wb1[o * 65];
    a.E1[o * 4 + 3] = 0.f;
    a.E2[o * 8 + 0] = a.b2[o];
    a.E2[o * 8 + 1] = a.Wg2[o * 65];
    a.E2[o * 8 + 2] = a.Wb2[o * 65];
    a.E2[o * 8 + 3] = a.W3[o];
    a.E2[o * 8 + 4] = a.W3[512 + o];
    a.E2[o * 8 + 5] = a.W3[1024 + o];
    a.E2[o * 8 + 6] = 0.f; a.E2[o * 8 + 7] = 0.f;
  }
  if (i < PTS * 3) {
    int d = i % 3;
    a.x_cur[i] = (a.x[i] - a.m1[d]) * __expf(a.lg1[d]) * rsqrtf(a.v1[d] + BN_EPS) + a.be1[d];
  }
  if (i < PTS) a.lp_state[i] = 0.f;
  {
    int lane = threadIdx.x & 63;
    int p = (blockIdx.x * 256 + threadIdx.x) >> 6;   // 0..8191
    float cv = a.c[(size_t)p * 64 + lane];
    float ag[3], ab[3];
    #pragma unroll
    for (int o = 0; o < 3; ++o) {
      ag[o] = cv * a.Wg3[o * 65 + 1 + lane];
      ab[o] = cv * a.Wb3[o * 65 + 1 + lane];
    }
    #pragma unroll
    for (int off = 32; off > 0; off >>= 1) {
      #pragma unroll
      for (int o = 0; o < 3; ++o) {
        ag[o] += __shfl_xor(ag[o], off);
        ab[o] += __shfl_xor(ab[o], off);
      }
    }
    if (lane == 0) {
      #pragma unroll
      for (int o = 0; o < 3; ++o) {
        a.G3[p * 3 + o] = ag[o] + a.bg3[o];
        a.B3[p * 3 + o] = ab[o];
      }
    }
  }
}

// ---------------------------------------------------------------- gates GEMM (bf16, proven)
struct GatesGemmArgs {
  const u16 *A, *W;
  const float* bias;
  u16* GBi;                // [3][8192][1024] interleaved
};
__global__ __launch_bounds__(256) void gates_gemm(GatesGemmArgs a) {
  __shared__ u16 As[128 * 32];
  __shared__ u16 Bs[128 * 32];
  int tid = threadIdx.x;
  int m0 = blockIdx.x * 128, n0 = blockIdx.y * 128;
  int wave = tid >> 6, lane = tid & 63;
  int wm = (wave & 1) * 64, wn = (wave >> 1) * 64;
  int lr = lane & 15, quad = lane >> 4;

  int rowS = tid >> 2, colS = (tid & 3) * 8;
  const u16* gA0 = a.A + (size_t)(m0 + rowS) * 64 + colS;
  const u16* gB0 = a.W + (size_t)(n0 + rowS) * 64 + colS;
  u16* sA0 = &As[tid * 8];
  u16* sA1 = &As[2048 + tid * 8];
  u16* sB0 = &Bs[tid * 8];
  u16* sB1 = &Bs[2048 + tid * 8];

  f32x4 acc[4][4];
  #pragma unroll
  for (int i = 0; i < 4; ++i)
    #pragma unroll
    for (int j = 0; j < 4; ++j)
      #pragma unroll
      for (int r = 0; r < 4; ++r) acc[i][j][r] = 0.f;

  for (int k0 = 0; k0 < 64; k0 += 32) {
    if (k0) __syncthreads();
    gl2lds16(gA0 + k0, sA0);
    gl2lds16(gA0 + (size_t)64 * 64 + k0, sA1);
    gl2lds16(gB0 + k0, sB0);
    gl2lds16(gB0 + (size_t)64 * 64 + k0, sB1);
    __syncthreads();
    s16x8 af[4], bfr[4];
    #pragma unroll
    for (int i = 0; i < 4; ++i)
      af[i] = *(const s16x8*)&As[(wm + i * 16 + lr) * 32 + quad * 8];
    #pragma unroll
    for (int j = 0; j < 4; ++j)
      bfr[j] = *(const s16x8*)&Bs[(wn + j * 16 + lr) * 32 + quad * 8];
    #pragma unroll
    for (int i = 0; i < 4; ++i)
      #pragma unroll
      for (int j = 0; j < 4; ++j)
        acc[i][j] = __builtin_amdgcn_mfma_f32_16x16x32_bf16(af[i], bfr[j], acc[i][j], 0, 0, 0);
  }

  #pragma unroll
  for (int j = 0; j < 4; ++j) {
    int n = n0 + wn + j * 16 + lr;
    int sec = n >> 9, col = n & 511;
    int l = (sec < 3) ? sec : sec - 3;
    int off = col * 2 + ((sec < 3) ? 0 : 1);
    float bv = a.bias[n];
    u16* outp = a.GBi + (size_t)l * PTS * 1024 + off;
    #pragma unroll
    for (int i = 0; i < 4; ++i) {
      int mrow = m0 + wm + i * 16 + quad * 4;
      #pragma unroll
      for (int r = 0; r < 4; ++r)
        outp[(size_t)(mrow + r) * 1024] = f2bf(acc[i][j][r] + bv);
    }
  }
}

// ---------------------------------------------------------------- per-stage kernel
// 512 blocks x 512 threads (8 waves); block owns 16 points (64 m-rows).
// W in frag-order; each wave reads ONLY its own 2KB/chunk slice -> W goes straight
// to registers, software-pipelined (coalesced lane*8 loads), ZERO K-loop barriers.
struct StageArgs {
  const float* sqrtT;
  float ts_prev, ts_cur;
  int mode_prev;             // -1 none, 0,1,2 stage folds, 3 step-end fold
  float* accum6;             // [PTS][6]
  const float *G3, *B3, *Wg3, *Wb3, *b3;
  float *x_cur, *kx, *kl, *lp_state;
  const u16 *GBi0, *GBi1, *GBi2;   // interleaved gate tables [PTS][1024]
  const float *E0, *E1, *E2;       // packed params
  const u8 *W1s, *W2s;             // fp8 weights frag-order [16][8][4][64][8]
};

__global__ __launch_bounds__(512, 4) void stage_kernel(StageArgs a) {
  __shared__ __align__(16) u8 Hs[64 * HSTRB];     // 33.8 KB (fp8 activations)
  __shared__ float xe[16][3];
  __shared__ float part[8][16][6];
  int tid = threadIdx.x;
  int w = tid >> 6, lane = tid & 63, lr = lane & 15, quad = lane >> 4;
  int n0 = w * 64;
  int p0 = blockIdx.x * 16;
  float s0 = a.sqrtT[0];
  float dt = s0 * s0 * (1.f / 3.f);

  // wave-local W slice base pointers (frag-order)
  const u8* w1l = a.W1s + (size_t)w * 2048 + (size_t)lane * 8;
  const u8* w2l = a.W2s + (size_t)w * 2048 + (size_t)lane * 8;

  // ---- preload W1 chunk 0 into registers (L2 latency overlaps fold + L0)
  i64 bc[4], bn[4];
  #pragma unroll
  for (int j = 0; j < 4; ++j) bc[j] = *(const i64*)(w1l + (size_t)j * 512);

  // ---- issue L0 gate loads EARLY (independent of fold)
  int pl0 = tid >> 5;
  int base_o = (tid & 31) * 16;
  const u16* g0row = a.GBi0 + (size_t)(p0 + pl0) * 1024 + 2 * base_o;
  u16x8 gc0 = *(const u16x8*)(g0row);
  u16x8 gc1 = *(const u16x8*)(g0row + 8);
  u16x8 gc2 = *(const u16x8*)(g0row + 16);
  u16x8 gc3 = *(const u16x8*)(g0row + 24);

  // ---- fold previous stage (thread per point)
  if (tid < 16) {
    int p = p0 + tid;
    float xc0 = a.x_cur[p * 3], xc1 = a.x_cur[p * 3 + 1], xc2 = a.x_cur[p * 3 + 2];
    float o0 = xc0, o1 = xc1, o2 = xc2;
    if (a.mode_prev >= 0) {
      float tp = a.ts_prev * dt;
      float dx[3], gate[3];
      #pragma unroll
      for (int r = 0; r < 3; ++r) {
        float fr = a.accum6[(size_t)p * 6 + r];
        gate[r] = sigf(a.G3[p * 3 + r] + tp * a.Wg3[r * 65]);
        float bias = a.B3[p * 3 + r] + tp * a.Wb3[r * 65];
        dx[r] = fmaf(fr + a.b3[r], gate[r], bias);
      }
      float klv = -(a.accum6[(size_t)p * 6 + 3] * gate[0] +
                    a.accum6[(size_t)p * 6 + 4] * gate[1] +
                    a.accum6[(size_t)p * 6 + 5] * gate[2]);
      int m = a.mode_prev;
      if (m == 0) {
        o0 = xc0 + 0.5f * dt * dx[0]; o1 = xc1 + 0.5f * dt * dx[1]; o2 = xc2 + 0.5f * dt * dx[2];
        a.kx[p * 3] = dx[0]; a.kx[p * 3 + 1] = dx[1]; a.kx[p * 3 + 2] = dx[2];
        a.kl[p] = klv;
      } else if (m == 1) {
        o0 = xc0 + 0.5f * dt * dx[0]; o1 = xc1 + 0.5f * dt * dx[1]; o2 = xc2 + 0.5f * dt * dx[2];
        a.kx[p * 3] += 2.f * dx[0]; a.kx[p * 3 + 1] += 2.f * dx[1]; a.kx[p * 3 + 2] += 2.f * dx[2];
        a.kl[p] += 2.f * klv;
      } else if (m == 2) {
        o0 = xc0 + dt * dx[0]; o1 = xc1 + dt * dx[1]; o2 = xc2 + dt * dx[2];
        a.kx[p * 3] += 2.f * dx[0]; a.kx[p * 3 + 1] += 2.f * dx[1]; a.kx[p * 3 + 2] += 2.f * dx[2];
        a.kl[p] += 2.f * klv;
      } else {
        float sc = dt * (1.f / 6.f);
        o0 = xc0 + sc * (a.kx[p * 3] + dx[0]);
        o1 = xc1 + sc * (a.kx[p * 3 + 1] + dx[1]);
        o2 = xc2 + sc * (a.kx[p * 3 + 2] + dx[2]);
        a.x_cur[p * 3] = o0; a.x_cur[p * 3 + 1] = o1; a.x_cur[p * 3 + 2] = o2;
        a.lp_state[p] += sc * (a.kl[p] + klv);
      }
    }
    xe[tid][0] = o0; xe[tid][1] = o1; xe[tid][2] = o2;
  }
  __syncthreads();

  float t = a.ts_cur * dt;

  // ---- layer0: 32 threads per point, 16 cols each -> H1 (fp8) in LDS
  {
    float x0 = xe[pl0][0], x1 = xe[pl0][1], x2 = xe[pl0][2];
    u16x8 gcv[4] = {gc0, gc1, gc2, gc3};
    #pragma unroll
    for (int cc = 0; cc < 4; ++cc) {
      u16x8 v = gcv[cc];
      float hk[4], d0k[4], d1k[4], d2k[4];
      #pragma unroll
      for (int k = 0; k < 4; ++k) {
        int o = base_o + cc * 4 + k;
        f32x4 e = *(const f32x4*)(a.E0 + (size_t)o * 8);
        f32x2 e2 = *(const f32x2*)(a.E0 + (size_t)o * 8 + 4);
        float u = fmaf(e[0], x0, fmaf(e[1], x1, e[2] * x2)) + e[3];
        float gate = sigf(bf2f(v[2 * k]) + t * e2[0]);
        float bias = bf2f(v[2 * k + 1]) + t * e2[1];
        float z = fmaf(u, gate, bias);
        float h = fast_tanh(z);
        float wm = (1.f - h * h) * gate * TS;
        hk[k] = h;
        d0k[k] = wm * e[0];
        d1k[k] = wm * e[1];
        d2k[k] = wm * e[2];
      }
      size_t hb = (size_t)(pl0 * 4) * HSTRB + base_o + cc * 4;
      *(unsigned*)(Hs + hb) = pk4_f8(hk[0], hk[1], hk[2], hk[3]);
      *(unsigned*)(Hs + hb + HSTRB) = pk4_f8(d0k[0], d0k[1], d0k[2], d0k[3]);
      *(unsigned*)(Hs + hb + 2 * HSTRB) = pk4_f8(d1k[0], d1k[1], d1k[2], d1k[3]);
      *(unsigned*)(Hs + hb + 3 * HSTRB) = pk4_f8(d2k[0], d2k[1], d2k[2], d2k[3]);
    }
  }

  // ---- prefetch epilogue-1 gate dwords (hidden behind GEMM1)
  unsigned g1v[4][4];
  #pragma unroll
  for (int j = 0; j < 4; ++j)
    #pragma unroll
    for (int i = 0; i < 4; ++i) {
      int n = n0 + j * 16 + lr;
      int p = p0 + i * 4 + quad;
      g1v[j][i] = *(const unsigned*)(a.GBi1 + (size_t)p * 1024 + 2 * n);
    }
  __syncthreads();   // H1 visible to all waves

  // ---- layer1 GEMM: register-pipelined W, NO barriers
  f32x4 acc[4][4];
  #pragma unroll
  for (int i = 0; i < 4; ++i)
    #pragma unroll
    for (int j = 0; j < 4; ++j)
      #pragma unroll
      for (int r = 0; r < 4; ++r) acc[i][j][r] = 0.f;
  {
    #pragma unroll 1
    for (int c = 0; c < 16; ++c) {
      const u8* nsrc = (c < 15) ? (w1l + (size_t)(c + 1) * 16384) : w2l;
      #pragma unroll
      for (int j = 0; j < 4; ++j) bn[j] = *(const i64*)(nsrc + (size_t)j * 512);
      int k0 = c * 32;
      i64 af[4];
      #pragma unroll
      for (int i = 0; i < 4; ++i)
        af[i] = *(const i64*)(Hs + (size_t)(i * 16 + lr) * HSTRB + k0 + quad * 8);
      #pragma unroll
      for (int i = 0; i < 4; ++i)
        #pragma unroll
        for (int j = 0; j < 4; ++j)
          acc[i][j] = __builtin_amdgcn_mfma_f32_16x16x32_fp8_fp8(af[i], bc[j], acc[i][j], 0, 0, 0);
      #pragma unroll
      for (int j = 0; j < 4; ++j) bc[j] = bn[j];
    }
  }
  __syncthreads();   // all H1 reads done -> safe to overwrite

  // ---- epilogue1 -> H2 (fp8) in same LDS (FULLY unrolled)
  #pragma unroll
  for (int j = 0; j < 4; ++j) {
    int n = n0 + j * 16 + lr;
    f32x4 e1 = *(const f32x4*)(a.E1 + (size_t)n * 4);
    #pragma unroll
    for (int i = 0; i < 4; ++i) {
      unsigned d = g1v[j][i];
      float gate = sigf(bf2f((u16)(d & 0xffffu)) + t * e1[1]);
      float bias = bf2f((u16)(d >> 16)) + t * e1[2];
      f32x4 u = acc[i][j];
      float z = fmaf(u[0] + e1[0], gate, bias);
      float h = fast_tanh(z);
      float wmf = (1.f - h * h) * gate;
      int row = i * 16 + quad * 4;
      Hs[(size_t)row * HSTRB + n] = f2f8(h);
      Hs[(size_t)(row + 1) * HSTRB + n] = f2f8(u[1] * wmf);
      Hs[(size_t)(row + 2) * HSTRB + n] = f2f8(u[2] * wmf);
      Hs[(size_t)(row + 3) * HSTRB + n] = f2f8(u[3] * wmf);
    }
  }

  // ---- prefetch epilogue-2 gate dwords (hidden behind GEMM2)
  unsigned g2v[4][4];
  #pragma unroll
  for (int j = 0; j < 4; ++j)
    #pragma unroll
    for (int i = 0; i < 4; ++i) {
      int n = n0 + j * 16 + lr;
      int p = p0 + i * 4 + quad;
      g2v[j][i] = *(const unsigned*)(a.GBi2 + (size_t)p * 1024 + 2 * n);
    }
  __syncthreads();   // H2 visible; bc already holds W2 chunk 0

  // ---- layer2 GEMM: register-pipelined W, NO barriers
  #pragma unroll
  for (int i = 0; i < 4; ++i)
    #pragma unroll
    for (int j = 0; j < 4; ++j)
      #pragma unroll
      for (int r = 0; r < 4; ++r) acc[i][j][r] = 0.f;
  {
    #pragma unroll 1
    for (int c = 0; c < 16; ++c) {
      if (c < 15) {
        const u8* nsrc = w2l + (size_t)(c + 1) * 16384;
        #pragma unroll
        for (int j = 0; j < 4; ++j) bn[j] = *(const i64*)(nsrc + (size_t)j * 512);
      }
      int k0 = c * 32;
      i64 af[4];
      #pragma unroll
      for (int i = 0; i < 4; ++i)
        af[i] = *(const i64*)(Hs + (size_t)(i * 16 + lr) * HSTRB + k0 + quad * 8);
      #pragma unroll
      for (int i = 0; i < 4; ++i)
        #pragma unroll
        for (int j = 0; j < 4; ++j)
          acc[i][j] = __builtin_amdgcn_mfma_f32_16x16x32_fp8_fp8(af[i], bc[j], acc[i][j], 0, 0, 0);
      if (c < 15) {
        #pragma unroll
        for (int j = 0; j < 4; ++j) bc[j] = bn[j];
      }
    }
  }

  // ---- epilogue2: gate/tanh + project onto W3 -> 6 partials per point
  #pragma unroll
  for (int i = 0; i < 4; ++i) {
    float v0 = 0.f, v1 = 0.f, v2 = 0.f, v3 = 0.f, v4 = 0.f, v5 = 0.f;
    int pl = i * 4 + quad;
    #pragma unroll
    for (int j = 0; j < 4; ++j) {
      int n = n0 + j * 16 + lr;
      f32x4 ea = *(const f32x4*)(a.E2 + (size_t)n * 8);
      f32x2 eb = *(const f32x2*)(a.E2 + (size_t)n * 8 + 4);
      unsigned d = g2v[j][i];
      float gate = sigf(bf2f((u16)(d & 0xffffu)) + t * ea[1]);
      float bias = bf2f((u16)(d >> 16)) + t * ea[2];
      f32x4 u = acc[i][j];
      float z = fmaf(u[0] + ea[0], gate, bias);
      float h = fast_tanh(z);
      float wmf = (1.f - h * h) * gate;
      float w30 = ea[3], w31 = eb[0], w32 = eb[1];
      v0 = fmaf(h, w30, v0);
      v1 = fmaf(h, w31, v1);
      v2 = fmaf(h, w32, v2);
      v3 = fmaf(u[1] * wmf, w30, v3);
      v4 = fmaf(u[2] * wmf, w31, v4);
      v5 = fmaf(u[3] * wmf, w32, v5);
    }
    #pragma unroll
    for (int mask = 1; mask <= 8; mask <<= 1) {
      v0 += __shfl_xor(v0, mask);
      v1 += __shfl_xor(v1, mask);
      v2 += __shfl_xor(v2, mask);
      v3 += __shfl_xor(v3, mask);
      v4 += __shfl_xor(v4, mask);
      v5 += __shfl_xor(v5, mask);
    }
    // tangent streams carry TS scale through both GEMMs -> undo here
    float val = (lr == 0) ? v0 : (lr == 1) ? v1 : (lr == 2) ? v2
              : (lr == 3) ? v3 * (1.f / TS) : (lr == 4) ? v4 * (1.f / TS)
              : v5 * (1.f / TS);
    if (lr < 6) part[w][pl][lr] = val;
  }
  __syncthreads();

  if (tid < 96) {
    int pt = tid / 6, d = tid - pt * 6;
    float sum = 0.f;
    #pragma unroll
    for (int ww = 0; ww < 8; ++ww) sum += part[ww][pt][d];
    a.accum6[(size_t)(p0 + pt) * 6 + d] = sum;
  }
}

// ---------------------------------------------------------------- finalize
struct FinArgs {
  const float* sqrtT;
  const float* accum6;
  const float *G3, *B3, *Wg3, *Wb3, *b3;
  float *x_cur, *kx, *kl, *lp_state;
  const float *m2, *v2, *lg2, *be2;
  float* out_x;
};
__global__ void finalize_kernel(FinArgs a) {
  int p = blockIdx.x * 256 + threadIdx.x;
  if (p >= PTS) return;
  float s0 = a.sqrtT[0];
  float dt = s0 * s0 * (1.f / 3.f);
  float tp = 3.f * dt;
  float dx[3], gate[3];
  #pragma unroll
  for (int r = 0; r < 3; ++r) {
    float fr = a.accum6[(size_t)p * 6 + r];
    gate[r] = sigf(a.G3[p * 3 + r] + tp * a.Wg3[r * 65]);
    float bias = a.B3[p * 3 + r] + tp * a.Wb3[r * 65];
    dx[r] = fmaf(fr + a.b3[r], gate[r], bias);
  }
  float klv = -(a.accum6[(size_t)p * 6 + 3] * gate[0] +
                a.accum6[(size_t)p * 6 + 4] * gate[1] +
                a.accum6[(size_t)p * 6 + 5] * gate[2]);
  float sc = dt * (1.f / 6.f);
  #pragma unroll
  for (int r = 0; r < 3; ++r) {
    float xf = a.x_cur[p * 3 + r] + sc * (a.kx[p * 3 + r] + dx[r]);
    a.out_x[p * 3 + r] = (xf - a.m2[r]) * __expf(a.lg2[r]) * rsqrtf(a.v2[r] + BN_EPS) + a.be2[r];
  }
  a.lp_state[p] += sc * (a.kl[p] + klv);
}

__global__ void finish_lp(const float* __restrict__ lp_state,
                          const float* __restrict__ v1, const float* __restrict__ lg1,
                          const float* __restrict__ v2, const float* __restrict__ lg2,
                          float* __restrict__ out) {
  int b = blockIdx.x, tid = threadIdx.x;
  float s = 0.f;
  for (int n = tid; n < 2048; n += 256) s += lp_state[b * 2048 + n];
  __shared__ float red[256];
  red[tid] = s;
  __syncthreads();
  for (int w = 128; w > 0; w >>= 1) {
    if (tid < w) red[tid] += red[tid + w];
    __syncthreads();
  }
  if (tid == 0) {
    float ld = 0.f;
    for (int d = 0; d < 3; ++d) {
      ld += lg1[d] - 0.5f * logf(v1[d] + BN_EPS);
      ld += lg2[d] - 0.5f * logf(v2[d] + BN_EPS);
    }
    out[b] = red[0] - 2048.f * ld;
  }
}

// ---------------------------------------------------------------- launch
extern "C" void kernel_launch(void* const* d_in, const int* in_sizes, int n_in,
                              void* d_out, int out_size, void* d_ws, size_t ws_size,
                              hipStream_t stream) {
  const float* x        = (const float*)d_in[0];
  const float* c        = (const float*)d_in[1];
  const float* bn1_mean = (const float*)d_in[2];
  const float* bn1_var  = (const float*)d_in[3];
  const float* bn1_lg   = (const float*)d_in[4];
  const float* bn1_beta = (const float*)d_in[5];
  const float* bn2_mean = (const float*)d_in[6];
  const float* bn2_var  = (const float*)d_in[7];
  const float* bn2_lg   = (const float*)d_in[8];
  const float* bn2_beta = (const float*)d_in[9];
  const float* sqrtT    = (const float*)d_in[10];
  const float* W0  = (const float*)d_in[11];
  const float* b0  = (const float*)d_in[12];
  const float* Wg0 = (const float*)d_in[13];
  const float* bg0 = (const float*)d_in[14];
  const float* Wb0 = (const float*)d_in[15];
  const float* W1  = (const float*)d_in[16];
  const float* b1  = (const float*)d_in[17];
  const float* Wg1 = (const float*)d_in[18];
  const float* bg1 = (const float*)d_in[19];
  const float* Wb1 = (const float*)d_in[20];
  const float* W2  = (const float*)d_in[21];
  const float* b2  = (const float*)d_in[22];
  const float* Wg2 = (const float*)d_in[23];
  const float* bg2 = (const float*)d_in[24];
  const float* Wb2 = (const float*)d_in[25];
  const float* W3  = (const float*)d_in[26];
  const float* b3  = (const float*)d_in[27];
  const float* Wg3 = (const float*)d_in[28];
  const float* bg3 = (const float*)d_in[29];
  const float* Wb3 = (const float*)d_in[30];

  char* base = (char*)d_ws;
  size_t off = 0;
  auto alloc = [&](size_t bytes) -> void* {
    void* pp = base + off;
    off += (bytes + 255) & ~(size_t)255;
    return pp;
  };
  u8* W1s = (u8*)alloc((size_t)512 * 512);
  u8* W2s = (u8*)alloc((size_t)512 * 512);
  u16* cb  = (u16*)alloc((size_t)PTS * 64 * 2);
  u16* Wpack = (u16*)alloc((size_t)6 * 512 * 64 * 2);
  float* bias_pack = (float*)alloc((size_t)3072 * 4);
  u16* GBi = (u16*)alloc((size_t)3 * PTS * 1024 * 2);
  const size_t SZi = (size_t)PTS * 1024;
  u16* GBi0 = GBi;
  u16* GBi1 = GBi + SZi;
  u16* GBi2 = GBi + 2 * SZi;
  float* G3f = (float*)alloc((size_t)PTS * 3 * 4);
  float* B3f = (float*)alloc((size_t)PTS * 3 * 4);
  float* E0 = (float*)alloc((size_t)512 * 8 * 4);
  float* E1 = (float*)alloc((size_t)512 * 4 * 4);
  float* E2 = (float*)alloc((size_t)512 * 8 * 4);
  float* accum6   = (float*)alloc((size_t)PTS * 6 * 4);
  float* x_cur    = (float*)alloc((size_t)PTS * 3 * 4);
  float* kx       = (float*)alloc((size_t)PTS * 3 * 4);
  float* kl       = (float*)alloc((size_t)PTS * 4);
  float* lp_state = (float*)alloc((size_t)PTS * 4);
  (void)ws_size; (void)in_sizes; (void)n_in; (void)out_size;

  PrepArgs pa{W1, W2, W1s, W2s, c, cb, Wg0, Wg1, Wg2, Wb0, Wb1, Wb2,
              bg0, bg1, bg2, Wpack, bias_pack, x, bn1_mean, bn1_var,
              bn1_lg, bn1_beta, x_cur, lp_state, Wg3, bg3, Wb3, G3f, B3f,
              W0, b0, b1, b2, W3, E0, E1, E2};
  prep_kernel<<<2048, 256, 0, stream>>>(pa);

  GatesGemmArgs gg{cb, Wpack, bias_pack, GBi};
  gates_gemm<<<dim3(64, 24), 256, 0, stream>>>(gg);

  auto ts_of = [](int s) -> float {
    static const float frac[4] = {0.f, 0.5f, 0.5f, 1.f};
    return (float)(s >> 2) + frac[s & 3];
  };

  for (int s = 0; s < 12; ++s) {
    StageArgs sa{sqrtT, (s == 0) ? 0.f : ts_of(s - 1), ts_of(s),
                 (s == 0) ? -1 : ((s - 1) & 3), accum6,
                 G3f, B3f, Wg3, Wb3, b3, x_cur, kx, kl, lp_state,
                 GBi0, GBi1, GBi2, E0, E1, E2, W1s, W2s};
    stage_kernel<<<PTS / 16, 512, 0, stream>>>(sa);
  }

  FinArgs fa{sqrtT, accum6, G3f, B3f, Wg3, Wb3, b3, x_cur, kx, kl,
             lp_state, bn2_mean, bn2_var, bn2_lg, bn2_beta, (float*)d_out};
  finalize_kernel<<<32, 256, 0, stream>>>(fa);
  finish_lp<<<4, 256, 0, stream>>>(lp_state, bn1_var, bn1_lg, bn2_var, bn2_lg,
                                   (float*)d_out + PTS * 3);
}